// Round 1
// baseline (249.857 us; speedup 1.0000x reference)
//
#include <hip/hip_runtime.h>
#include <stdint.h>

// Problem constants
#define BATCH 4
#define CH 256
#define NPIX 4096
#define NGROUP 8
#define GCH 32
#define EPSV 1e-5f

typedef __attribute__((ext_vector_type(8))) short bf16x8;   // 8 bf16 = 4 VGPRs
typedef __attribute__((ext_vector_type(4))) float f32x4;

#define MFMA_B16(a, b, c) __builtin_amdgcn_mfma_f32_16x16x32_bf16((a), (b), (c), 0, 0, 0)

// global -> LDS direct copy, 16B per lane; LDS dest must be wave-uniform base
#define GLOAD16(gsrc, ldst)                                                        \
  __builtin_amdgcn_global_load_lds(                                               \
      (const __attribute__((address_space(1))) uint32_t*)(gsrc),                  \
      (__attribute__((address_space(3))) uint32_t*)(ldst), 16, 0, 0)

__device__ __forceinline__ unsigned short f2bf(float f) {
  union { float f; uint32_t u; } v; v.f = f;
  return (unsigned short)((v.u + 0x7FFFu + ((v.u >> 16) & 1u)) >> 16);
}

// ---------------------------------------------------------------------------
// Weight conversion: fp32 -> bf16; fold attention scale 1/16 into Wq and bq
// ---------------------------------------------------------------------------
__global__ __launch_bounds__(256) void wconv(
    const float* __restrict__ Wq, const float* __restrict__ Wk,
    const float* __restrict__ Wv, const float* __restrict__ Wo,
    const float* __restrict__ bq,
    unsigned short* __restrict__ Wq_b, unsigned short* __restrict__ Wk_b,
    unsigned short* __restrict__ Wv_b, unsigned short* __restrict__ Wo_b,
    float* __restrict__ bq_s) {
  int i = blockIdx.x * 256 + threadIdx.x;   // 65536 per weight
  Wq_b[i] = f2bf(Wq[i] * 0.0625f);
  Wk_b[i] = f2bf(Wk[i]);
  Wv_b[i] = f2bf(Wv[i]);
  Wo_b[i] = f2bf(Wo[i]);
  if (i < CH) bq_s[i] = bq[i] * 0.0625f;
}

// ---------------------------------------------------------------------------
// GroupNorm pass 1: per-(b,c) partial sums (deterministic; no atomics)
// ---------------------------------------------------------------------------
__global__ __launch_bounds__(256) void gn_stats(const float* __restrict__ x,
                                                float* __restrict__ part) {
  int bc = blockIdx.x;                       // 0 .. B*C-1
  const float* row = x + (size_t)bc * NPIX;
  int t = threadIdx.x;
  float s = 0.f, ss = 0.f;
  #pragma unroll
  for (int i = 0; i < 4; ++i) {
    f32x4 v = *(const f32x4*)(row + (i * 256 + t) * 4);
    s += v[0] + v[1] + v[2] + v[3];
    ss += v[0]*v[0] + v[1]*v[1] + v[2]*v[2] + v[3]*v[3];
  }
  #pragma unroll
  for (int m = 1; m < 64; m <<= 1) { s += __shfl_xor(s, m); ss += __shfl_xor(ss, m); }
  __shared__ float ls[8];
  if ((t & 63) == 0) { ls[(t >> 6) * 2] = s; ls[(t >> 6) * 2 + 1] = ss; }
  __syncthreads();
  if (t == 0) {
    part[bc * 2]     = ls[0] + ls[2] + ls[4] + ls[6];
    part[bc * 2 + 1] = ls[1] + ls[3] + ls[5] + ls[7];
  }
}

// ---------------------------------------------------------------------------
// GroupNorm pass 2: normalize + affine, write h transposed (B*N, C) as bf16
// ---------------------------------------------------------------------------
__global__ __launch_bounds__(256) void gn_apply(
    const float* __restrict__ x, const float* __restrict__ part,
    const float* __restrict__ gamma, const float* __restrict__ beta,
    unsigned short* __restrict__ h_t) {
  int chunk = blockIdx.x, g = blockIdx.y, b = blockIdx.z;
  int t = threadIdx.x;
  __shared__ float s_mean, s_rstd;
  __shared__ unsigned short tile[GCH][72];   // +pad
  if (t == 0) {
    float S = 0.f, SS = 0.f;
    const float* p = part + (size_t)(b * CH + g * GCH) * 2;
    for (int j = 0; j < GCH; ++j) { S += p[2 * j]; SS += p[2 * j + 1]; }
    float inv = 1.0f / (float)(GCH * NPIX);
    float mean = S * inv;
    float var = SS * inv - mean * mean;
    s_mean = mean;
    s_rstd = rsqrtf(var + EPSV);
  }
  __syncthreads();
  float mean = s_mean, rstd = s_rstd;
  int n0 = chunk * 64;
  int p = t & 63;
  int csub = t >> 6;
  #pragma unroll
  for (int cl = 0; cl < GCH; cl += 4) {
    int c = cl + csub;
    float val = x[(size_t)(b * CH + g * GCH + c) * NPIX + n0 + p];
    float gm = gamma[g * GCH + c], bt = beta[g * GCH + c];
    tile[c][p] = f2bf((val - mean) * rstd * gm + bt);
  }
  __syncthreads();
  int pix = t >> 2, cc = (t & 3) * 8;
  bf16x8 vv;
  #pragma unroll
  for (int j = 0; j < 8; ++j) vv[j] = (short)tile[cc + j][pix];
  *(bf16x8*)(h_t + (size_t)(b * NPIX + n0 + pix) * CH + g * GCH + cc) = vv;
}

// ---------------------------------------------------------------------------
// GEMM: C[M,N] = A[M,256]bf16 * Bt[N,256]bf16^T (+bias, +resid)
// 128x128 tile, BK=64, 4 waves (2x2), XOR-swizzled LDS, global_load_lds w16
// ---------------------------------------------------------------------------
template <int BIAS_COL, int RESID, int OUT_BF16>
__global__ __launch_bounds__(256, 2) void gemm_bt_k(
    const unsigned short* __restrict__ A, const unsigned short* __restrict__ Bt,
    void* __restrict__ Cout, const float* __restrict__ bias,
    const float* __restrict__ resid, int M, int N,
    long aStride, long btStride, long cStride) {
  __shared__ __align__(16) unsigned short a_lds[128 * 64];
  __shared__ __align__(16) unsigned short b_lds[128 * 64];

  const int bz = blockIdx.z;
  const char* Ac = (const char*)(A + (size_t)bz * aStride);
  const char* Bc = (const char*)(Bt + (size_t)bz * btStride);
  const int m0 = blockIdx.x * 128;
  const int n0 = blockIdx.y * 128;
  const int t = threadIdx.x;
  const int w = t >> 6, l = t & 63, lr = l & 15, lk = l >> 4;
  const int wr = (w >> 1) * 64, wc = (w & 1) * 64;

  f32x4 acc[4][4];
  #pragma unroll
  for (int i = 0; i < 4; ++i)
    #pragma unroll
    for (int j = 0; j < 4; ++j) acc[i][j] = f32x4{0.f, 0.f, 0.f, 0.f};

  char* alc = (char*)a_lds;
  char* blc = (char*)b_lds;

  for (int kt = 0; kt < 4; ++kt) {
    __syncthreads();
    #pragma unroll
    for (int i = 0; i < 4; ++i) {
      int base = i * 4096 + w * 1024;
      int lin = base + l * 16;
      int sw = lin ^ (((lin >> 7) & 7) << 4);   // rows are 128B; swizzle 16B chunk
      int row = lin >> 7;
      int inr = sw & 127;
      GLOAD16(Ac + (size_t)(m0 + row) * 512 + kt * 128 + inr, alc + base);
      GLOAD16(Bc + (size_t)(n0 + row) * 512 + kt * 128 + inr, blc + base);
    }
    __syncthreads();
    #pragma unroll
    for (int ks = 0; ks < 2; ++ks) {
      bf16x8 af[4], bf[4];
      #pragma unroll
      for (int f = 0; f < 4; ++f) {
        int ra = wr + f * 16 + lr;
        int la = ra * 128 + ks * 64 + lk * 16;
        af[f] = *(const bf16x8*)(alc + (la ^ ((ra & 7) << 4)));
        int rb = wc + f * 16 + lr;
        int lb = rb * 128 + ks * 64 + lk * 16;
        bf[f] = *(const bf16x8*)(blc + (lb ^ ((rb & 7) << 4)));
      }
      #pragma unroll
      for (int mf = 0; mf < 4; ++mf)
        #pragma unroll
        for (int nf = 0; nf < 4; ++nf)
          acc[mf][nf] = MFMA_B16(af[mf], bf[nf], acc[mf][nf]);
    }
  }

  #pragma unroll
  for (int mf = 0; mf < 4; ++mf) {
    #pragma unroll
    for (int nf = 0; nf < 4; ++nf) {
      int col = n0 + wc + nf * 16 + lr;
      #pragma unroll
      for (int r = 0; r < 4; ++r) {
        int row = m0 + wr + mf * 16 + lk * 4 + r;   // C/D: col=lane&15, row=(lane>>4)*4+reg
        float val = acc[mf][nf][r];
        val += BIAS_COL ? bias[col] : bias[row];
        size_t idx = (size_t)bz * (size_t)cStride + (size_t)row * N + col;
        if (RESID) val += resid[idx];
        if (OUT_BF16) ((unsigned short*)Cout)[idx] = f2bf(val);
        else          ((float*)Cout)[idx] = val;
      }
    }
  }
}

// ---------------------------------------------------------------------------
// Flash attention: QBLK=64 (4 waves x 16 rows), KBLK=128, D=256
// q_t,k_t: (B*N, D) bf16 (q pre-scaled by 1/16); v: (B, D, N) bf16
// ---------------------------------------------------------------------------
__global__ __launch_bounds__(256, 1) void flash_kernel(
    const unsigned short* __restrict__ q_t, const unsigned short* __restrict__ k_t,
    const unsigned short* __restrict__ v, unsigned short* __restrict__ out_t) {
  __shared__ __align__(16) unsigned short k_lds[128 * 256];   // 64KB, swizzled
  __shared__ __align__(16) unsigned short v_lds[256 * 128];   // 64KB, swizzled
  __shared__ __align__(16) unsigned short p_lds[4][16][136];  // padded, per-wave

  const int b = blockIdx.y;
  const int q0 = blockIdx.x * 64;
  const int t = threadIdx.x;
  const int w = t >> 6, l = t & 63, lr = l & 15, lk = l >> 4;

  // Q fragments: 16 rows per wave, 8 d-steps of 32
  bf16x8 qf[8];
  {
    const unsigned short* qp = q_t + (size_t)(b * NPIX + q0 + w * 16 + lr) * CH + lk * 8;
    #pragma unroll
    for (int ds = 0; ds < 8; ++ds) qf[ds] = *(const bf16x8*)(qp + ds * 32);
  }

  f32x4 oacc[16];
  #pragma unroll
  for (int i = 0; i < 16; ++i) oacc[i] = f32x4{0.f, 0.f, 0.f, 0.f};
  float m_r[4] = {-3e38f, -3e38f, -3e38f, -3e38f};
  float l_r[4] = {0.f, 0.f, 0.f, 0.f};

  const char* kg = (const char*)(k_t + (size_t)b * NPIX * CH);
  const char* vg = (const char*)(v + (size_t)b * CH * NPIX);
  char* klc = (char*)k_lds;
  char* vlc = (char*)v_lds;

  for (int it = 0; it < NPIX / 128; ++it) {
    __syncthreads();   // all waves done reading previous K/V tiles
    {
      const char* src = kg + (size_t)it * 128 * CH * 2;   // contiguous 64KB
      #pragma unroll
      for (int i = 0; i < 16; ++i) {
        int base = i * 4096 + w * 1024;
        int lin = base + l * 16;
        int s = lin ^ (((lin >> 9) & 7) << 4);            // K rows = 512B
        GLOAD16(src + s, klc + base);
      }
      const char* vsrc = vg + (size_t)it * 128 * 2;
      #pragma unroll
      for (int i = 0; i < 16; ++i) {
        int base = i * 4096 + w * 1024;
        int lin = base + l * 16;
        int sw = lin ^ (((lin >> 8) & 7) << 4);           // V rows = 256B
        GLOAD16(vsrc + (size_t)(lin >> 8) * 8192 + (sw & 255), vlc + base);
      }
    }
    __syncthreads();   // compiler drains vmcnt(0) before barrier

    // S = Q K^T  (16 x 128 strip per wave)
    f32x4 sacc[8];
    #pragma unroll
    for (int i = 0; i < 8; ++i) sacc[i] = f32x4{0.f, 0.f, 0.f, 0.f};
    #pragma unroll
    for (int ds = 0; ds < 8; ++ds) {
      #pragma unroll
      for (int mf = 0; mf < 8; ++mf) {
        int row = mf * 16 + lr;
        int lin = row * 512 + ds * 64 + lk * 16;
        bf16x8 kf = *(const bf16x8*)(klc + (lin ^ ((row & 7) << 4)));
        sacc[mf] = MFMA_B16(qf[ds], kf, sacc[mf]);
      }
    }

    // online softmax; row = lk*4 + r; 16 lanes (lr) share a row
    float rmax[4];
    #pragma unroll
    for (int r = 0; r < 4; ++r) {
      float mx = sacc[0][r];
      #pragma unroll
      for (int mf = 1; mf < 8; ++mf) mx = fmaxf(mx, sacc[mf][r]);
      #pragma unroll
      for (int msk = 1; msk < 16; msk <<= 1) mx = fmaxf(mx, __shfl_xor(mx, msk));
      rmax[r] = mx;
    }
    bool nochg = (rmax[0] <= m_r[0]) & (rmax[1] <= m_r[1]) &
                 (rmax[2] <= m_r[2]) & (rmax[3] <= m_r[3]);
    if (!__all(nochg)) {   // alpha==1 skip: exact (only skip when max unchanged)
      #pragma unroll
      for (int r = 0; r < 4; ++r) {
        float mn = fmaxf(m_r[r], rmax[r]);
        float al = __expf(m_r[r] - mn);
        m_r[r] = mn;
        l_r[r] *= al;
        #pragma unroll
        for (int cf = 0; cf < 16; ++cf) oacc[cf][r] *= al;
      }
    }
    float rsum[4] = {0.f, 0.f, 0.f, 0.f};
    #pragma unroll
    for (int mf = 0; mf < 8; ++mf) {
      #pragma unroll
      for (int r = 0; r < 4; ++r) {
        float p = __expf(sacc[mf][r] - m_r[r]);
        rsum[r] += p;
        p_lds[w][lk * 4 + r][mf * 16 + lr] = f2bf(p);
      }
    }
    #pragma unroll
    for (int r = 0; r < 4; ++r) {
      float s = rsum[r];
      #pragma unroll
      for (int msk = 1; msk < 16; msk <<= 1) s += __shfl_xor(s, msk);
      l_r[r] += s;
    }

    // O += P V^T : A = P (16 x 128), B-frag from v_lds (c-major)
    #pragma unroll
    for (int ms = 0; ms < 4; ++ms) {
      bf16x8 ap = *(const bf16x8*)(&p_lds[w][lr][ms * 32 + lk * 8]);
      #pragma unroll
      for (int cf = 0; cf < 16; ++cf) {
        int row = cf * 16 + lr;
        int lin = row * 256 + ms * 64 + lk * 16;
        bf16x8 bv = *(const bf16x8*)(vlc + (lin ^ ((row & 7) << 4)));
        oacc[cf] = MFMA_B16(ap, bv, oacc[cf]);
      }
    }
  }

  // epilogue: O /= l, write out_t (B*N, C) bf16
  {
    float invl[4];
    #pragma unroll
    for (int r = 0; r < 4; ++r) invl[r] = 1.0f / l_r[r];
    unsigned short* op = out_t + (size_t)(b * NPIX + q0 + w * 16) * CH;
    #pragma unroll
    for (int cf = 0; cf < 16; ++cf)
      #pragma unroll
      for (int r = 0; r < 4; ++r)
        op[(size_t)(lk * 4 + r) * CH + cf * 16 + lr] = f2bf(oacc[cf][r] * invl[r]);
  }
}

// ---------------------------------------------------------------------------
extern "C" void kernel_launch(void* const* d_in, const int* in_sizes, int n_in,
                              void* d_out, int out_size, void* d_ws, size_t ws_size,
                              hipStream_t stream) {
  const float* x   = (const float*)d_in[0];
  const float* gsc = (const float*)d_in[1];
  const float* gbi = (const float*)d_in[2];
  const float* Wq  = (const float*)d_in[3];
  const float* bq  = (const float*)d_in[4];
  const float* Wk  = (const float*)d_in[5];
  const float* bk  = (const float*)d_in[6];
  const float* Wv  = (const float*)d_in[7];
  const float* bv  = (const float*)d_in[8];
  const float* Wo  = (const float*)d_in[9];
  const float* bo  = (const float*)d_in[10];

  char* ws = (char*)d_ws;
  unsigned short* Wq_b = (unsigned short*)(ws);
  unsigned short* Wk_b = (unsigned short*)(ws + 131072);
  unsigned short* Wv_b = (unsigned short*)(ws + 262144);
  unsigned short* Wo_b = (unsigned short*)(ws + 393216);
  float* bq_s          = (float*)(ws + 524288);
  float* part          = (float*)(ws + 525312);
  char* big            = ws + 533504;
  unsigned short* h_t  = (unsigned short*)(big);                      // (B*N, C) bf16
  unsigned short* q_t  = (unsigned short*)(big + 1 * 8388608ull);     // (B*N, C)
  unsigned short* k_t  = (unsigned short*)(big + 2 * 8388608ull);     // (B*N, C)
  unsigned short* v_   = (unsigned short*)(big + 3 * 8388608ull);     // (B, C, N)
  unsigned short* o_t  = (unsigned short*)(big + 4 * 8388608ull);     // (B*N, C)
  if (ws_size < 533504 + 5ull * 8388608ull) return;

  wconv<<<256, 256, 0, stream>>>(Wq, Wk, Wv, Wo, bq, Wq_b, Wk_b, Wv_b, Wo_b, bq_s);
  gn_stats<<<BATCH * CH, 256, 0, stream>>>(x, part);
  gn_apply<<<dim3(64, NGROUP, BATCH), 256, 0, stream>>>(x, part, gsc, gbi, h_t);

  // q_t = h_t @ (Wq/16)^T + bq/16 ; k_t = h_t @ Wk^T + bk   (M=16384, N=256)
  gemm_bt_k<1, 0, 1><<<dim3(128, 2, 1), 256, 0, stream>>>(
      h_t, Wq_b, q_t, bq_s, nullptr, 16384, 256, 0, 0, 0);
  gemm_bt_k<1, 0, 1><<<dim3(128, 2, 1), 256, 0, stream>>>(
      h_t, Wk_b, k_t, bk, nullptr, 16384, 256, 0, 0, 0);
  // v = Wv @ h + bv, stored (C, N) per batch  (M=256, N=4096)
  gemm_bt_k<0, 0, 1><<<dim3(2, 32, BATCH), 256, 0, stream>>>(
      Wv_b, h_t, v_, bv, nullptr, 256, 4096, 0, 1048576, 1048576);

  flash_kernel<<<dim3(64, BATCH), 256, 0, stream>>>(q_t, k_t, v_, o_t);

  // out = Wo @ attn_out + bo + input  (fp32, (B, C, N))
  gemm_bt_k<0, 1, 0><<<dim3(2, 32, BATCH), 256, 0, stream>>>(
      Wo_b, o_t, (float*)d_out, bo, x, 256, 4096, 0, 1048576, 1048576);
}

// Round 2
// 249.715 us; speedup vs baseline: 1.0006x; 1.0006x over previous
//
#include <hip/hip_runtime.h>
#include <stdint.h>

// Problem constants
#define BATCH 4
#define CH 256
#define NPIX 4096
#define NGROUP 8
#define GCH 32
#define EPSV 1e-5f

typedef __attribute__((ext_vector_type(8))) short bf16x8;   // 8 bf16 = 4 VGPRs
typedef __attribute__((ext_vector_type(4))) float f32x4;

#define MFMA_B16(a, b, c) __builtin_amdgcn_mfma_f32_16x16x32_bf16((a), (b), (c), 0, 0, 0)

// global -> LDS direct copy, 16B per lane; LDS dest must be wave-uniform base
#define GLOAD16(gsrc, ldst)                                                        \
  __builtin_amdgcn_global_load_lds(                                               \
      (const __attribute__((address_space(1))) uint32_t*)(gsrc),                  \
      (__attribute__((address_space(3))) uint32_t*)(ldst), 16, 0, 0)

__device__ __forceinline__ unsigned short f2bf(float f) {
  union { float f; uint32_t u; } v; v.f = f;
  return (unsigned short)((v.u + 0x7FFFu + ((v.u >> 16) & 1u)) >> 16);
}

// ---------------------------------------------------------------------------
// Weight conversion: fp32 -> bf16; fold attention scale 1/16 into Wq and bq
// ---------------------------------------------------------------------------
__global__ __launch_bounds__(256) void wconv(
    const float* __restrict__ Wq, const float* __restrict__ Wk,
    const float* __restrict__ Wv, const float* __restrict__ Wo,
    const float* __restrict__ bq,
    unsigned short* __restrict__ Wq_b, unsigned short* __restrict__ Wk_b,
    unsigned short* __restrict__ Wv_b, unsigned short* __restrict__ Wo_b,
    float* __restrict__ bq_s) {
  int i = blockIdx.x * 256 + threadIdx.x;   // 65536 per weight
  Wq_b[i] = f2bf(Wq[i] * 0.0625f);
  Wk_b[i] = f2bf(Wk[i]);
  Wv_b[i] = f2bf(Wv[i]);
  Wo_b[i] = f2bf(Wo[i]);
  if (i < CH) bq_s[i] = bq[i] * 0.0625f;
}

// ---------------------------------------------------------------------------
// GroupNorm pass 1: per-(b,c) partial sums (deterministic; no atomics)
// ---------------------------------------------------------------------------
__global__ __launch_bounds__(256) void gn_stats(const float* __restrict__ x,
                                                float* __restrict__ part) {
  int bc = blockIdx.x;                       // 0 .. B*C-1
  const float* row = x + (size_t)bc * NPIX;
  int t = threadIdx.x;
  float s = 0.f, ss = 0.f;
  #pragma unroll
  for (int i = 0; i < 4; ++i) {
    f32x4 v = *(const f32x4*)(row + (i * 256 + t) * 4);
    s += v[0] + v[1] + v[2] + v[3];
    ss += v[0]*v[0] + v[1]*v[1] + v[2]*v[2] + v[3]*v[3];
  }
  #pragma unroll
  for (int m = 1; m < 64; m <<= 1) { s += __shfl_xor(s, m); ss += __shfl_xor(ss, m); }
  __shared__ float ls[8];
  if ((t & 63) == 0) { ls[(t >> 6) * 2] = s; ls[(t >> 6) * 2 + 1] = ss; }
  __syncthreads();
  if (t == 0) {
    part[bc * 2]     = ls[0] + ls[2] + ls[4] + ls[6];
    part[bc * 2 + 1] = ls[1] + ls[3] + ls[5] + ls[7];
  }
}

// ---------------------------------------------------------------------------
// GroupNorm pass 2: normalize + affine, write h transposed (B*N, C) as bf16
// ---------------------------------------------------------------------------
__global__ __launch_bounds__(256) void gn_apply(
    const float* __restrict__ x, const float* __restrict__ part,
    const float* __restrict__ gamma, const float* __restrict__ beta,
    unsigned short* __restrict__ h_t) {
  int chunk = blockIdx.x, g = blockIdx.y, b = blockIdx.z;
  int t = threadIdx.x;
  __shared__ float s_mean, s_rstd;
  __shared__ unsigned short tile[GCH][72];   // +pad
  if (t == 0) {
    float S = 0.f, SS = 0.f;
    const float* p = part + (size_t)(b * CH + g * GCH) * 2;
    for (int j = 0; j < GCH; ++j) { S += p[2 * j]; SS += p[2 * j + 1]; }
    float inv = 1.0f / (float)(GCH * NPIX);
    float mean = S * inv;
    float var = SS * inv - mean * mean;
    s_mean = mean;
    s_rstd = rsqrtf(var + EPSV);
  }
  __syncthreads();
  float mean = s_mean, rstd = s_rstd;
  int n0 = chunk * 64;
  int p = t & 63;
  int csub = t >> 6;
  #pragma unroll
  for (int cl = 0; cl < GCH; cl += 4) {
    int c = cl + csub;
    float val = x[(size_t)(b * CH + g * GCH + c) * NPIX + n0 + p];
    float gm = gamma[g * GCH + c], bt = beta[g * GCH + c];
    tile[c][p] = f2bf((val - mean) * rstd * gm + bt);
  }
  __syncthreads();
  int pix = t >> 2, cc = (t & 3) * 8;
  bf16x8 vv;
  #pragma unroll
  for (int j = 0; j < 8; ++j) vv[j] = (short)tile[cc + j][pix];
  *(bf16x8*)(h_t + (size_t)(b * NPIX + n0 + pix) * CH + g * GCH + cc) = vv;
}

// ---------------------------------------------------------------------------
// GEMM: C[M,N] = A[M,256]bf16 * Bt[N,256]bf16^T (+bias, +resid)
// 128x128 tile, BK=64, 4 waves (2x2), XOR-swizzled LDS, global_load_lds w16
// ---------------------------------------------------------------------------
template <int BIAS_COL, int RESID, int OUT_BF16>
__global__ __launch_bounds__(256, 2) void gemm_bt_k(
    const unsigned short* __restrict__ A, const unsigned short* __restrict__ Bt,
    void* __restrict__ Cout, const float* __restrict__ bias,
    const float* __restrict__ resid, int M, int N,
    long aStride, long btStride, long cStride) {
  __shared__ __align__(16) unsigned short a_lds[128 * 64];
  __shared__ __align__(16) unsigned short b_lds[128 * 64];

  const int bz = blockIdx.z;
  const char* Ac = (const char*)(A + (size_t)bz * aStride);
  const char* Bc = (const char*)(Bt + (size_t)bz * btStride);
  const int m0 = blockIdx.x * 128;
  const int n0 = blockIdx.y * 128;
  const int t = threadIdx.x;
  const int w = t >> 6, l = t & 63, lr = l & 15, lk = l >> 4;
  const int wr = (w >> 1) * 64, wc = (w & 1) * 64;

  f32x4 acc[4][4];
  #pragma unroll
  for (int i = 0; i < 4; ++i)
    #pragma unroll
    for (int j = 0; j < 4; ++j) acc[i][j] = f32x4{0.f, 0.f, 0.f, 0.f};

  char* alc = (char*)a_lds;
  char* blc = (char*)b_lds;

  for (int kt = 0; kt < 4; ++kt) {
    __syncthreads();
    #pragma unroll
    for (int i = 0; i < 4; ++i) {
      int base = i * 4096 + w * 1024;
      int lin = base + l * 16;
      int sw = lin ^ (((lin >> 7) & 7) << 4);   // rows are 128B; swizzle 16B chunk
      int row = lin >> 7;
      int inr = sw & 127;
      GLOAD16(Ac + (size_t)(m0 + row) * 512 + kt * 128 + inr, alc + base);
      GLOAD16(Bc + (size_t)(n0 + row) * 512 + kt * 128 + inr, blc + base);
    }
    __syncthreads();
    #pragma unroll
    for (int ks = 0; ks < 2; ++ks) {
      bf16x8 af[4], bf[4];
      #pragma unroll
      for (int f = 0; f < 4; ++f) {
        int ra = wr + f * 16 + lr;
        int la = ra * 128 + ks * 64 + lk * 16;
        af[f] = *(const bf16x8*)(alc + (la ^ ((ra & 7) << 4)));
        int rb = wc + f * 16 + lr;
        int lb = rb * 128 + ks * 64 + lk * 16;
        bf[f] = *(const bf16x8*)(blc + (lb ^ ((rb & 7) << 4)));
      }
      #pragma unroll
      for (int mf = 0; mf < 4; ++mf)
        #pragma unroll
        for (int nf = 0; nf < 4; ++nf)
          acc[mf][nf] = MFMA_B16(af[mf], bf[nf], acc[mf][nf]);
    }
  }

  #pragma unroll
  for (int mf = 0; mf < 4; ++mf) {
    #pragma unroll
    for (int nf = 0; nf < 4; ++nf) {
      int col = n0 + wc + nf * 16 + lr;
      #pragma unroll
      for (int r = 0; r < 4; ++r) {
        int row = m0 + wr + mf * 16 + lk * 4 + r;   // C/D: col=lane&15, row=(lane>>4)*4+reg
        float val = acc[mf][nf][r];
        val += BIAS_COL ? bias[col] : bias[row];
        size_t idx = (size_t)bz * (size_t)cStride + (size_t)row * N + col;
        if (RESID) val += resid[idx];
        if (OUT_BF16) ((unsigned short*)Cout)[idx] = f2bf(val);
        else          ((float*)Cout)[idx] = val;
      }
    }
  }
}

// ---------------------------------------------------------------------------
// Flash attention: QBLK=64 (4 waves x 16 rows), KBLK=128, D=256
// q_t,k_t: (B*N, D) bf16 (q pre-scaled by 1/16); v: (B, D, N) bf16
// ---------------------------------------------------------------------------
__global__ __launch_bounds__(256, 1) void flash_kernel(
    const unsigned short* __restrict__ q_t, const unsigned short* __restrict__ k_t,
    const unsigned short* __restrict__ v, unsigned short* __restrict__ out_t) {
  __shared__ __align__(16) unsigned short k_lds[128 * 256];   // 64KB, swizzled
  __shared__ __align__(16) unsigned short v_lds[256 * 128];   // 64KB, swizzled
  __shared__ __align__(16) unsigned short p_lds[4][16][136];  // padded, per-wave

  const int b = blockIdx.y;
  const int q0 = blockIdx.x * 64;
  const int t = threadIdx.x;
  const int w = t >> 6, l = t & 63, lr = l & 15, lk = l >> 4;

  // Q fragments: 16 rows per wave, 8 d-steps of 32
  bf16x8 qf[8];
  {
    const unsigned short* qp = q_t + (size_t)(b * NPIX + q0 + w * 16 + lr) * CH + lk * 8;
    #pragma unroll
    for (int ds = 0; ds < 8; ++ds) qf[ds] = *(const bf16x8*)(qp + ds * 32);
  }

  f32x4 oacc[16];
  #pragma unroll
  for (int i = 0; i < 16; ++i) oacc[i] = f32x4{0.f, 0.f, 0.f, 0.f};
  float m_r[4] = {-3e38f, -3e38f, -3e38f, -3e38f};
  float l_r[4] = {0.f, 0.f, 0.f, 0.f};

  const char* kg = (const char*)(k_t + (size_t)b * NPIX * CH);
  const char* vg = (const char*)(v + (size_t)b * CH * NPIX);
  char* klc = (char*)k_lds;
  char* vlc = (char*)v_lds;

  for (int it = 0; it < NPIX / 128; ++it) {
    __syncthreads();   // all waves done reading previous K/V tiles
    {
      const char* src = kg + (size_t)it * 128 * CH * 2;   // contiguous 64KB
      #pragma unroll
      for (int i = 0; i < 16; ++i) {
        int base = i * 4096 + w * 1024;
        int lin = base + l * 16;
        int s = lin ^ (((lin >> 9) & 7) << 4);            // K rows = 512B
        GLOAD16(src + s, klc + base);
      }
      const char* vsrc = vg + (size_t)it * 128 * 2;
      #pragma unroll
      for (int i = 0; i < 16; ++i) {
        int base = i * 4096 + w * 1024;
        int lin = base + l * 16;
        int sw = lin ^ (((lin >> 8) & 7) << 4);           // V rows = 256B
        GLOAD16(vsrc + (size_t)(lin >> 8) * 8192 + (sw & 255), vlc + base);
      }
    }
    __syncthreads();   // compiler drains vmcnt(0) before barrier

    // S = Q K^T  (16 x 128 strip per wave)
    f32x4 sacc[8];
    #pragma unroll
    for (int i = 0; i < 8; ++i) sacc[i] = f32x4{0.f, 0.f, 0.f, 0.f};
    #pragma unroll
    for (int ds = 0; ds < 8; ++ds) {
      #pragma unroll
      for (int mf = 0; mf < 8; ++mf) {
        int row = mf * 16 + lr;
        int lin = row * 512 + ds * 64 + lk * 16;
        bf16x8 kf = *(const bf16x8*)(klc + (lin ^ ((row & 7) << 4)));
        sacc[mf] = MFMA_B16(qf[ds], kf, sacc[mf]);
      }
    }

    // online softmax; row = lk*4 + r; 16 lanes (lr) share a row
    float rmax[4];
    #pragma unroll
    for (int r = 0; r < 4; ++r) {
      float mx = sacc[0][r];
      #pragma unroll
      for (int mf = 1; mf < 8; ++mf) mx = fmaxf(mx, sacc[mf][r]);
      #pragma unroll
      for (int msk = 1; msk < 16; msk <<= 1) mx = fmaxf(mx, __shfl_xor(mx, msk));
      rmax[r] = mx;
    }
    bool nochg = (rmax[0] <= m_r[0]) & (rmax[1] <= m_r[1]) &
                 (rmax[2] <= m_r[2]) & (rmax[3] <= m_r[3]);
    if (!__all(nochg)) {   // alpha==1 skip: exact (only skip when max unchanged)
      #pragma unroll
      for (int r = 0; r < 4; ++r) {
        float mn = fmaxf(m_r[r], rmax[r]);
        float al = __expf(m_r[r] - mn);
        m_r[r] = mn;
        l_r[r] *= al;
        #pragma unroll
        for (int cf = 0; cf < 16; ++cf) oacc[cf][r] *= al;
      }
    }
    float rsum[4] = {0.f, 0.f, 0.f, 0.f};
    #pragma unroll
    for (int mf = 0; mf < 8; ++mf) {
      #pragma unroll
      for (int r = 0; r < 4; ++r) {
        float p = __expf(sacc[mf][r] - m_r[r]);
        rsum[r] += p;
        p_lds[w][lk * 4 + r][mf * 16 + lr] = f2bf(p);
      }
    }
    #pragma unroll
    for (int r = 0; r < 4; ++r) {
      float s = rsum[r];
      #pragma unroll
      for (int msk = 1; msk < 16; msk <<= 1) s += __shfl_xor(s, msk);
      l_r[r] += s;
    }

    // O += P V^T : A = P (16 x 128), B-frag from v_lds (c-major)
    #pragma unroll
    for (int ms = 0; ms < 4; ++ms) {
      bf16x8 ap = *(const bf16x8*)(&p_lds[w][lr][ms * 32 + lk * 8]);
      #pragma unroll
      for (int cf = 0; cf < 16; ++cf) {
        int row = cf * 16 + lr;
        int lin = row * 256 + ms * 64 + lk * 16;
        bf16x8 bv = *(const bf16x8*)(vlc + (lin ^ ((row & 7) << 4)));
        oacc[cf] = MFMA_B16(ap, bv, oacc[cf]);
      }
    }
  }

  // epilogue: O /= l, write out_t (B*N, C) bf16
  {
    float invl[4];
    #pragma unroll
    for (int r = 0; r < 4; ++r) invl[r] = 1.0f / l_r[r];
    unsigned short* op = out_t + (size_t)(b * NPIX + q0 + w * 16) * CH;
    #pragma unroll
    for (int cf = 0; cf < 16; ++cf)
      #pragma unroll
      for (int r = 0; r < 4; ++r)
        op[(size_t)(lk * 4 + r) * CH + cf * 16 + lr] = f2bf(oacc[cf][r] * invl[r]);
  }
}

// ---------------------------------------------------------------------------
extern "C" void kernel_launch(void* const* d_in, const int* in_sizes, int n_in,
                              void* d_out, int out_size, void* d_ws, size_t ws_size,
                              hipStream_t stream) {
  const float* x   = (const float*)d_in[0];
  const float* gsc = (const float*)d_in[1];
  const float* gbi = (const float*)d_in[2];
  const float* Wq  = (const float*)d_in[3];
  const float* bq  = (const float*)d_in[4];
  const float* Wk  = (const float*)d_in[5];
  const float* bk  = (const float*)d_in[6];
  const float* Wv  = (const float*)d_in[7];
  const float* bv  = (const float*)d_in[8];
  const float* Wo  = (const float*)d_in[9];
  const float* bo  = (const float*)d_in[10];

  char* ws = (char*)d_ws;
  unsigned short* Wq_b = (unsigned short*)(ws);
  unsigned short* Wk_b = (unsigned short*)(ws + 131072);
  unsigned short* Wv_b = (unsigned short*)(ws + 262144);
  unsigned short* Wo_b = (unsigned short*)(ws + 393216);
  float* bq_s          = (float*)(ws + 524288);
  float* part          = (float*)(ws + 525312);
  char* big            = ws + 533504;
  unsigned short* h_t  = (unsigned short*)(big);                      // (B*N, C) bf16
  unsigned short* q_t  = (unsigned short*)(big + 1 * 8388608ull);     // (B*N, C)
  unsigned short* k_t  = (unsigned short*)(big + 2 * 8388608ull);     // (B*N, C)
  unsigned short* v_   = (unsigned short*)(big + 3 * 8388608ull);     // (B, C, N)
  unsigned short* o_t  = (unsigned short*)(big + 4 * 8388608ull);     // (B*N, C)
  if (ws_size < 533504 + 5ull * 8388608ull) return;

  wconv<<<256, 256, 0, stream>>>(Wq, Wk, Wv, Wo, bq, Wq_b, Wk_b, Wv_b, Wo_b, bq_s);
  gn_stats<<<BATCH * CH, 256, 0, stream>>>(x, part);
  gn_apply<<<dim3(64, NGROUP, BATCH), 256, 0, stream>>>(x, part, gsc, gbi, h_t);

  // q_t = h_t @ (Wq/16)^T + bq/16 ; k_t = h_t @ Wk^T + bk   (M=16384, N=256)
  gemm_bt_k<1, 0, 1><<<dim3(128, 2, 1), 256, 0, stream>>>(
      h_t, Wq_b, q_t, bq_s, nullptr, 16384, 256, 0, 0, 0);
  gemm_bt_k<1, 0, 1><<<dim3(128, 2, 1), 256, 0, stream>>>(
      h_t, Wk_b, k_t, bk, nullptr, 16384, 256, 0, 0, 0);
  // v = Wv @ h + bv, stored (C, N) per batch  (M=256, N=4096)
  gemm_bt_k<0, 0, 1><<<dim3(2, 32, BATCH), 256, 0, stream>>>(
      Wv_b, h_t, v_, bv, nullptr, 256, 4096, 0, 1048576, 1048576);

  flash_kernel<<<dim3(64, BATCH), 256, 0, stream>>>(q_t, k_t, v_, o_t);

  // out = Wo @ attn_out + bo + input  (fp32, (B, C, N))
  gemm_bt_k<0, 1, 0><<<dim3(2, 32, BATCH), 256, 0, stream>>>(
      Wo_b, o_t, (float*)d_out, bo, x, 256, 4096, 0, 1048576, 1048576);
}

// Round 3
// 248.908 us; speedup vs baseline: 1.0038x; 1.0032x over previous
//
#include <hip/hip_runtime.h>
#include <stdint.h>

// Problem constants
#define BATCH 4
#define CH 256
#define NPIX 4096
#define NGROUP 8
#define GCH 32
#define EPSV 1e-5f

typedef __attribute__((ext_vector_type(8))) short bf16x8;   // 8 bf16 = 4 VGPRs
typedef __attribute__((ext_vector_type(4))) float f32x4;

#define MFMA_B16(a, b, c) __builtin_amdgcn_mfma_f32_16x16x32_bf16((a), (b), (c), 0, 0, 0)

// global -> LDS direct copy, 16B per lane; LDS dest must be wave-uniform base
#define GLOAD16(gsrc, ldst)                                                        \
  __builtin_amdgcn_global_load_lds(                                               \
      (const __attribute__((address_space(1))) uint32_t*)(gsrc),                  \
      (__attribute__((address_space(3))) uint32_t*)(ldst), 16, 0, 0)

__device__ __forceinline__ unsigned short f2bf(float f) {
  union { float f; uint32_t u; } v; v.f = f;
  return (unsigned short)((v.u + 0x7FFFu + ((v.u >> 16) & 1u)) >> 16);
}

// ---------------------------------------------------------------------------
// Weight conversion: fp32 -> bf16; fold attention scale 1/16 into Wq and bq
// ---------------------------------------------------------------------------
__global__ __launch_bounds__(256) void wconv(
    const float* __restrict__ Wq, const float* __restrict__ Wk,
    const float* __restrict__ Wv, const float* __restrict__ Wo,
    const float* __restrict__ bq,
    unsigned short* __restrict__ Wq_b, unsigned short* __restrict__ Wk_b,
    unsigned short* __restrict__ Wv_b, unsigned short* __restrict__ Wo_b,
    float* __restrict__ bq_s) {
  int i = blockIdx.x * 256 + threadIdx.x;   // 65536 per weight
  Wq_b[i] = f2bf(Wq[i] * 0.0625f);
  Wk_b[i] = f2bf(Wk[i]);
  Wv_b[i] = f2bf(Wv[i]);
  Wo_b[i] = f2bf(Wo[i]);
  if (i < CH) bq_s[i] = bq[i] * 0.0625f;
}

// ---------------------------------------------------------------------------
// GroupNorm pass 1: per-(b,c) partial sums (deterministic; no atomics)
// ---------------------------------------------------------------------------
__global__ __launch_bounds__(256) void gn_stats(const float* __restrict__ x,
                                                float* __restrict__ part) {
  int bc = blockIdx.x;                       // 0 .. B*C-1
  const float* row = x + (size_t)bc * NPIX;
  int t = threadIdx.x;
  float s = 0.f, ss = 0.f;
  #pragma unroll
  for (int i = 0; i < 4; ++i) {
    f32x4 v = *(const f32x4*)(row + (i * 256 + t) * 4);
    s += v[0] + v[1] + v[2] + v[3];
    ss += v[0]*v[0] + v[1]*v[1] + v[2]*v[2] + v[3]*v[3];
  }
  #pragma unroll
  for (int m = 1; m < 64; m <<= 1) { s += __shfl_xor(s, m); ss += __shfl_xor(ss, m); }
  __shared__ float ls[8];
  if ((t & 63) == 0) { ls[(t >> 6) * 2] = s; ls[(t >> 6) * 2 + 1] = ss; }
  __syncthreads();
  if (t == 0) {
    part[bc * 2]     = ls[0] + ls[2] + ls[4] + ls[6];
    part[bc * 2 + 1] = ls[1] + ls[3] + ls[5] + ls[7];
  }
}

// ---------------------------------------------------------------------------
// GroupNorm pass 2: normalize + affine, write h transposed (B*N, C) as bf16
// ---------------------------------------------------------------------------
__global__ __launch_bounds__(256) void gn_apply(
    const float* __restrict__ x, const float* __restrict__ part,
    const float* __restrict__ gamma, const float* __restrict__ beta,
    unsigned short* __restrict__ h_t) {
  int chunk = blockIdx.x, g = blockIdx.y, b = blockIdx.z;
  int t = threadIdx.x;
  __shared__ float s_mean, s_rstd;
  __shared__ unsigned short tile[GCH][72];   // +pad
  if (t == 0) {
    float S = 0.f, SS = 0.f;
    const float* p = part + (size_t)(b * CH + g * GCH) * 2;
    for (int j = 0; j < GCH; ++j) { S += p[2 * j]; SS += p[2 * j + 1]; }
    float inv = 1.0f / (float)(GCH * NPIX);
    float mean = S * inv;
    float var = SS * inv - mean * mean;
    s_mean = mean;
    s_rstd = rsqrtf(var + EPSV);
  }
  __syncthreads();
  float mean = s_mean, rstd = s_rstd;
  int n0 = chunk * 64;
  int p = t & 63;
  int csub = t >> 6;
  #pragma unroll
  for (int cl = 0; cl < GCH; cl += 4) {
    int c = cl + csub;
    float val = x[(size_t)(b * CH + g * GCH + c) * NPIX + n0 + p];
    float gm = gamma[g * GCH + c], bt = beta[g * GCH + c];
    tile[c][p] = f2bf((val - mean) * rstd * gm + bt);
  }
  __syncthreads();
  int pix = t >> 2, cc = (t & 3) * 8;
  bf16x8 vv;
  #pragma unroll
  for (int j = 0; j < 8; ++j) vv[j] = (short)tile[cc + j][pix];
  *(bf16x8*)(h_t + (size_t)(b * NPIX + n0 + pix) * CH + g * GCH + cc) = vv;
}

// ---------------------------------------------------------------------------
// GEMM: C[M,N] = A[M,256]bf16 * Bt[N,256]bf16^T (+bias, +resid)
// 128x128 tile, BK=64, 4 waves (2x2), XOR-swizzled LDS, global_load_lds w16
// ---------------------------------------------------------------------------
template <int BIAS_COL, int RESID, int OUT_BF16>
__global__ __launch_bounds__(256, 2) void gemm_bt_k(
    const unsigned short* __restrict__ A, const unsigned short* __restrict__ Bt,
    void* __restrict__ Cout, const float* __restrict__ bias,
    const float* __restrict__ resid, int M, int N,
    long aStride, long btStride, long cStride) {
  __shared__ __align__(16) unsigned short a_lds[128 * 64];
  __shared__ __align__(16) unsigned short b_lds[128 * 64];

  const int bz = blockIdx.z;
  const char* Ac = (const char*)(A + (size_t)bz * aStride);
  const char* Bc = (const char*)(Bt + (size_t)bz * btStride);
  const int m0 = blockIdx.x * 128;
  const int n0 = blockIdx.y * 128;
  const int t = threadIdx.x;
  const int w = t >> 6, l = t & 63, lr = l & 15, lk = l >> 4;
  const int wr = (w >> 1) * 64, wc = (w & 1) * 64;

  f32x4 acc[4][4];
  #pragma unroll
  for (int i = 0; i < 4; ++i)
    #pragma unroll
    for (int j = 0; j < 4; ++j) acc[i][j] = f32x4{0.f, 0.f, 0.f, 0.f};

  char* alc = (char*)a_lds;
  char* blc = (char*)b_lds;

  for (int kt = 0; kt < 4; ++kt) {
    __syncthreads();
    #pragma unroll
    for (int i = 0; i < 4; ++i) {
      int base = i * 4096 + w * 1024;
      int lin = base + l * 16;
      int sw = lin ^ (((lin >> 7) & 7) << 4);   // rows are 128B; swizzle 16B chunk
      int row = lin >> 7;
      int inr = sw & 127;
      GLOAD16(Ac + (size_t)(m0 + row) * 512 + kt * 128 + inr, alc + base);
      GLOAD16(Bc + (size_t)(n0 + row) * 512 + kt * 128 + inr, blc + base);
    }
    __syncthreads();
    #pragma unroll
    for (int ks = 0; ks < 2; ++ks) {
      bf16x8 af[4], bf[4];
      #pragma unroll
      for (int f = 0; f < 4; ++f) {
        int ra = wr + f * 16 + lr;
        int la = ra * 128 + ks * 64 + lk * 16;
        af[f] = *(const bf16x8*)(alc + (la ^ ((ra & 7) << 4)));
        int rb = wc + f * 16 + lr;
        int lb = rb * 128 + ks * 64 + lk * 16;
        bf[f] = *(const bf16x8*)(blc + (lb ^ ((rb & 7) << 4)));
      }
      #pragma unroll
      for (int mf = 0; mf < 4; ++mf)
        #pragma unroll
        for (int nf = 0; nf < 4; ++nf)
          acc[mf][nf] = MFMA_B16(af[mf], bf[nf], acc[mf][nf]);
    }
  }

  #pragma unroll
  for (int mf = 0; mf < 4; ++mf) {
    #pragma unroll
    for (int nf = 0; nf < 4; ++nf) {
      int col = n0 + wc + nf * 16 + lr;
      #pragma unroll
      for (int r = 0; r < 4; ++r) {
        int row = m0 + wr + mf * 16 + lk * 4 + r;   // C/D: col=lane&15, row=(lane>>4)*4+reg
        float val = acc[mf][nf][r];
        val += BIAS_COL ? bias[col] : bias[row];
        size_t idx = (size_t)bz * (size_t)cStride + (size_t)row * N + col;
        if (RESID) val += resid[idx];
        if (OUT_BF16) ((unsigned short*)Cout)[idx] = f2bf(val);
        else          ((float*)Cout)[idx] = val;
      }
    }
  }
}

// ---------------------------------------------------------------------------
// Flash attention: QBLK=64 (4 waves x 16 rows), KBLK=128, D=256
// q_t,k_t: (B*N, D) bf16 (q pre-scaled by 1/16); v: (B, D, N) bf16
// ---------------------------------------------------------------------------
__global__ __launch_bounds__(256, 1) void flash_kernel(
    const unsigned short* __restrict__ q_t, const unsigned short* __restrict__ k_t,
    const unsigned short* __restrict__ v, unsigned short* __restrict__ out_t) {
  __shared__ __align__(16) unsigned short k_lds[128 * 256];   // 64KB, swizzled
  __shared__ __align__(16) unsigned short v_lds[256 * 128];   // 64KB, swizzled
  __shared__ __align__(16) unsigned short p_lds[4][16][136];  // padded, per-wave

  const int b = blockIdx.y;
  const int q0 = blockIdx.x * 64;
  const int t = threadIdx.x;
  const int w = t >> 6, l = t & 63, lr = l & 15, lk = l >> 4;

  // Q fragments: 16 rows per wave, 8 d-steps of 32
  bf16x8 qf[8];
  {
    const unsigned short* qp = q_t + (size_t)(b * NPIX + q0 + w * 16 + lr) * CH + lk * 8;
    #pragma unroll
    for (int ds = 0; ds < 8; ++ds) qf[ds] = *(const bf16x8*)(qp + ds * 32);
  }

  f32x4 oacc[16];
  #pragma unroll
  for (int i = 0; i < 16; ++i) oacc[i] = f32x4{0.f, 0.f, 0.f, 0.f};
  float m_r[4] = {-3e38f, -3e38f, -3e38f, -3e38f};
  float l_r[4] = {0.f, 0.f, 0.f, 0.f};

  const char* kg = (const char*)(k_t + (size_t)b * NPIX * CH);
  const char* vg = (const char*)(v + (size_t)b * CH * NPIX);
  char* klc = (char*)k_lds;
  char* vlc = (char*)v_lds;

  for (int it = 0; it < NPIX / 128; ++it) {
    __syncthreads();   // all waves done reading previous K/V tiles
    {
      const char* src = kg + (size_t)it * 128 * CH * 2;   // contiguous 64KB
      #pragma unroll
      for (int i = 0; i < 16; ++i) {
        int base = i * 4096 + w * 1024;
        int lin = base + l * 16;
        int s = lin ^ (((lin >> 9) & 7) << 4);            // K rows = 512B
        GLOAD16(src + s, klc + base);
      }
      const char* vsrc = vg + (size_t)it * 128 * 2;
      #pragma unroll
      for (int i = 0; i < 16; ++i) {
        int base = i * 4096 + w * 1024;
        int lin = base + l * 16;
        int sw = lin ^ (((lin >> 8) & 7) << 4);           // V rows = 256B
        GLOAD16(vsrc + (size_t)(lin >> 8) * 8192 + (sw & 255), vlc + base);
      }
    }
    __syncthreads();   // compiler drains vmcnt(0) before barrier

    // S = Q K^T  (16 x 128 strip per wave)
    f32x4 sacc[8];
    #pragma unroll
    for (int i = 0; i < 8; ++i) sacc[i] = f32x4{0.f, 0.f, 0.f, 0.f};
    #pragma unroll
    for (int ds = 0; ds < 8; ++ds) {
      #pragma unroll
      for (int mf = 0; mf < 8; ++mf) {
        int row = mf * 16 + lr;
        int lin = row * 512 + ds * 64 + lk * 16;
        bf16x8 kf = *(const bf16x8*)(klc + (lin ^ ((row & 7) << 4)));
        sacc[mf] = MFMA_B16(qf[ds], kf, sacc[mf]);
      }
    }

    // online softmax; row = lk*4 + r; 16 lanes (lr) share a row
    float rmax[4];
    #pragma unroll
    for (int r = 0; r < 4; ++r) {
      float mx = sacc[0][r];
      #pragma unroll
      for (int mf = 1; mf < 8; ++mf) mx = fmaxf(mx, sacc[mf][r]);
      #pragma unroll
      for (int msk = 1; msk < 16; msk <<= 1) mx = fmaxf(mx, __shfl_xor(mx, msk));
      rmax[r] = mx;
    }
    bool nochg = (rmax[0] <= m_r[0]) & (rmax[1] <= m_r[1]) &
                 (rmax[2] <= m_r[2]) & (rmax[3] <= m_r[3]);
    if (!__all(nochg)) {   // alpha==1 skip: exact (only skip when max unchanged)
      #pragma unroll
      for (int r = 0; r < 4; ++r) {
        float mn = fmaxf(m_r[r], rmax[r]);
        float al = __expf(m_r[r] - mn);
        m_r[r] = mn;
        l_r[r] *= al;
        #pragma unroll
        for (int cf = 0; cf < 16; ++cf) oacc[cf][r] *= al;
      }
    }
    float rsum[4] = {0.f, 0.f, 0.f, 0.f};
    #pragma unroll
    for (int mf = 0; mf < 8; ++mf) {
      #pragma unroll
      for (int r = 0; r < 4; ++r) {
        float p = __expf(sacc[mf][r] - m_r[r]);
        rsum[r] += p;
        p_lds[w][lk * 4 + r][mf * 16 + lr] = f2bf(p);
      }
    }
    #pragma unroll
    for (int r = 0; r < 4; ++r) {
      float s = rsum[r];
      #pragma unroll
      for (int msk = 1; msk < 16; msk <<= 1) s += __shfl_xor(s, msk);
      l_r[r] += s;
    }

    // O += P V^T : A = P (16 x 128), B-frag from v_lds (c-major)
    #pragma unroll
    for (int ms = 0; ms < 4; ++ms) {
      bf16x8 ap = *(const bf16x8*)(&p_lds[w][lr][ms * 32 + lk * 8]);
      #pragma unroll
      for (int cf = 0; cf < 16; ++cf) {
        int row = cf * 16 + lr;
        int lin = row * 256 + ms * 64 + lk * 16;
        bf16x8 bv = *(const bf16x8*)(vlc + (lin ^ ((row & 7) << 4)));
        oacc[cf] = MFMA_B16(ap, bv, oacc[cf]);
      }
    }
  }

  // epilogue: O /= l, write out_t (B*N, C) bf16
  {
    float invl[4];
    #pragma unroll
    for (int r = 0; r < 4; ++r) invl[r] = 1.0f / l_r[r];
    unsigned short* op = out_t + (size_t)(b * NPIX + q0 + w * 16) * CH;
    #pragma unroll
    for (int cf = 0; cf < 16; ++cf)
      #pragma unroll
      for (int r = 0; r < 4; ++r)
        op[(size_t)(lk * 4 + r) * CH + cf * 16 + lr] = f2bf(oacc[cf][r] * invl[r]);
  }
}

// ---------------------------------------------------------------------------
extern "C" void kernel_launch(void* const* d_in, const int* in_sizes, int n_in,
                              void* d_out, int out_size, void* d_ws, size_t ws_size,
                              hipStream_t stream) {
  const float* x   = (const float*)d_in[0];
  const float* gsc = (const float*)d_in[1];
  const float* gbi = (const float*)d_in[2];
  const float* Wq  = (const float*)d_in[3];
  const float* bq  = (const float*)d_in[4];
  const float* Wk  = (const float*)d_in[5];
  const float* bk  = (const float*)d_in[6];
  const float* Wv  = (const float*)d_in[7];
  const float* bv  = (const float*)d_in[8];
  const float* Wo  = (const float*)d_in[9];
  const float* bo  = (const float*)d_in[10];

  char* ws = (char*)d_ws;
  unsigned short* Wq_b = (unsigned short*)(ws);
  unsigned short* Wk_b = (unsigned short*)(ws + 131072);
  unsigned short* Wv_b = (unsigned short*)(ws + 262144);
  unsigned short* Wo_b = (unsigned short*)(ws + 393216);
  float* bq_s          = (float*)(ws + 524288);
  float* part          = (float*)(ws + 525312);
  char* big            = ws + 533504;
  unsigned short* h_t  = (unsigned short*)(big);                      // (B*N, C) bf16
  unsigned short* q_t  = (unsigned short*)(big + 1 * 8388608ull);     // (B*N, C)
  unsigned short* k_t  = (unsigned short*)(big + 2 * 8388608ull);     // (B*N, C)
  unsigned short* v_   = (unsigned short*)(big + 3 * 8388608ull);     // (B, C, N)
  unsigned short* o_t  = (unsigned short*)(big + 4 * 8388608ull);     // (B*N, C)
  if (ws_size < 533504 + 5ull * 8388608ull) return;

  wconv<<<256, 256, 0, stream>>>(Wq, Wk, Wv, Wo, bq, Wq_b, Wk_b, Wv_b, Wo_b, bq_s);
  gn_stats<<<BATCH * CH, 256, 0, stream>>>(x, part);
  gn_apply<<<dim3(64, NGROUP, BATCH), 256, 0, stream>>>(x, part, gsc, gbi, h_t);

  // q_t = h_t @ (Wq/16)^T + bq/16 ; k_t = h_t @ Wk^T + bk   (M=16384, N=256)
  gemm_bt_k<1, 0, 1><<<dim3(128, 2, 1), 256, 0, stream>>>(
      h_t, Wq_b, q_t, bq_s, nullptr, 16384, 256, 0, 0, 0);
  gemm_bt_k<1, 0, 1><<<dim3(128, 2, 1), 256, 0, stream>>>(
      h_t, Wk_b, k_t, bk, nullptr, 16384, 256, 0, 0, 0);
  // v = Wv @ h + bv, stored (C, N) per batch  (M=256, N=4096)
  gemm_bt_k<0, 0, 1><<<dim3(2, 32, BATCH), 256, 0, stream>>>(
      Wv_b, h_t, v_, bv, nullptr, 256, 4096, 0, 1048576, 1048576);

  flash_kernel<<<dim3(64, BATCH), 256, 0, stream>>>(q_t, k_t, v_, o_t);

  // out = Wo @ attn_out + bo + input  (fp32, (B, C, N))
  gemm_bt_k<0, 1, 0><<<dim3(2, 32, BATCH), 256, 0, stream>>>(
      Wo_b, o_t, (float*)d_out, bo, x, 256, 4096, 0, 1048576, 1048576);
}

// Round 4
// 241.842 us; speedup vs baseline: 1.0331x; 1.0292x over previous
//
#include <hip/hip_runtime.h>
#include <stdint.h>

// Problem constants
#define BATCH 4
#define CH 256
#define NPIX 4096
#define NGROUP 8
#define GCH 32
#define EPSV 1e-5f

typedef __attribute__((ext_vector_type(8))) short bf16x8;   // 8 bf16 = 4 VGPRs
typedef __attribute__((ext_vector_type(4))) float f32x4;

#define MFMA_B16(a, b, c) __builtin_amdgcn_mfma_f32_16x16x32_bf16((a), (b), (c), 0, 0, 0)

// global -> LDS direct copy, 16B per lane; LDS dest must be wave-uniform base
#define GLOAD16(gsrc, ldst)                                                        \
  __builtin_amdgcn_global_load_lds(                                               \
      (const __attribute__((address_space(1))) uint32_t*)(gsrc),                  \
      (__attribute__((address_space(3))) uint32_t*)(ldst), 16, 0, 0)

__device__ __forceinline__ unsigned short f2bf(float f) {
  union { float f; uint32_t u; } v; v.f = f;
  return (unsigned short)((v.u + 0x7FFFu + ((v.u >> 16) & 1u)) >> 16);
}
__device__ __forceinline__ float bf2f(unsigned short h) {
  union { uint32_t u; float f; } v; v.u = ((uint32_t)h) << 16;
  return v.f;
}

// ---------------------------------------------------------------------------
// Weight conversion: fp32 -> bf16; fold attention scale 1/16 into Wq and bq
// ---------------------------------------------------------------------------
__global__ __launch_bounds__(256) void wconv(
    const float* __restrict__ Wq, const float* __restrict__ Wk,
    const float* __restrict__ Wv, const float* __restrict__ Wo,
    const float* __restrict__ bq,
    unsigned short* __restrict__ Wq_b, unsigned short* __restrict__ Wk_b,
    unsigned short* __restrict__ Wv_b, unsigned short* __restrict__ Wo_b,
    float* __restrict__ bq_s) {
  int i = blockIdx.x * 256 + threadIdx.x;   // 65536 per weight
  Wq_b[i] = f2bf(Wq[i] * 0.0625f);
  Wk_b[i] = f2bf(Wk[i]);
  Wv_b[i] = f2bf(Wv[i]);
  Wo_b[i] = f2bf(Wo[i]);
  if (i < CH) bq_s[i] = bq[i] * 0.0625f;
}

// ---------------------------------------------------------------------------
// GroupNorm pass 1: per-(b,c) partial sums (deterministic; no atomics)
// ---------------------------------------------------------------------------
__global__ __launch_bounds__(256) void gn_stats(const float* __restrict__ x,
                                                float* __restrict__ part) {
  int bc = blockIdx.x;                       // 0 .. B*C-1
  const float* row = x + (size_t)bc * NPIX;
  int t = threadIdx.x;
  float s = 0.f, ss = 0.f;
  #pragma unroll
  for (int i = 0; i < 4; ++i) {
    f32x4 v = *(const f32x4*)(row + (i * 256 + t) * 4);
    s += v[0] + v[1] + v[2] + v[3];
    ss += v[0]*v[0] + v[1]*v[1] + v[2]*v[2] + v[3]*v[3];
  }
  #pragma unroll
  for (int m = 1; m < 64; m <<= 1) { s += __shfl_xor(s, m); ss += __shfl_xor(ss, m); }
  __shared__ float ls[8];
  if ((t & 63) == 0) { ls[(t >> 6) * 2] = s; ls[(t >> 6) * 2 + 1] = ss; }
  __syncthreads();
  if (t == 0) {
    part[bc * 2]     = ls[0] + ls[2] + ls[4] + ls[6];
    part[bc * 2 + 1] = ls[1] + ls[3] + ls[5] + ls[7];
  }
}

// ---------------------------------------------------------------------------
// GroupNorm pass 2: normalize + affine, write h transposed (B*N, C) as bf16
// ---------------------------------------------------------------------------
__global__ __launch_bounds__(256) void gn_apply(
    const float* __restrict__ x, const float* __restrict__ part,
    const float* __restrict__ gamma, const float* __restrict__ beta,
    unsigned short* __restrict__ h_t) {
  int chunk = blockIdx.x, g = blockIdx.y, b = blockIdx.z;
  int t = threadIdx.x;
  __shared__ float s_mean, s_rstd;
  __shared__ unsigned short tile[GCH][72];   // +pad
  if (t == 0) {
    float S = 0.f, SS = 0.f;
    const float* p = part + (size_t)(b * CH + g * GCH) * 2;
    for (int j = 0; j < GCH; ++j) { S += p[2 * j]; SS += p[2 * j + 1]; }
    float inv = 1.0f / (float)(GCH * NPIX);
    float mean = S * inv;
    float var = SS * inv - mean * mean;
    s_mean = mean;
    s_rstd = rsqrtf(var + EPSV);
  }
  __syncthreads();
  float mean = s_mean, rstd = s_rstd;
  int n0 = chunk * 64;
  int p = t & 63;
  int csub = t >> 6;
  #pragma unroll
  for (int cl = 0; cl < GCH; cl += 4) {
    int c = cl + csub;
    float val = x[(size_t)(b * CH + g * GCH + c) * NPIX + n0 + p];
    float gm = gamma[g * GCH + c], bt = beta[g * GCH + c];
    tile[c][p] = f2bf((val - mean) * rstd * gm + bt);
  }
  __syncthreads();
  int pix = t >> 2, cc = (t & 3) * 8;
  bf16x8 vv;
  #pragma unroll
  for (int j = 0; j < 8; ++j) vv[j] = (short)tile[cc + j][pix];
  *(bf16x8*)(h_t + (size_t)(b * NPIX + n0 + pix) * CH + g * GCH + cc) = vv;
}

// ---------------------------------------------------------------------------
// GEMM: C[M,N] = A[M,256]bf16 * Bt[N,256]bf16^T (+bias, +resid)
// 128x128 tile, BK=64, 4 waves (2x2), XOR-swizzled LDS, global_load_lds w16
// ---------------------------------------------------------------------------
template <int BIAS_COL, int RESID, int OUT_BF16>
__global__ __launch_bounds__(256, 2) void gemm_bt_k(
    const unsigned short* __restrict__ A, const unsigned short* __restrict__ Bt,
    void* __restrict__ Cout, const float* __restrict__ bias,
    const float* __restrict__ resid, int M, int N,
    long aStride, long btStride, long cStride) {
  __shared__ __align__(16) unsigned short a_lds[128 * 64];
  __shared__ __align__(16) unsigned short b_lds[128 * 64];

  const int bz = blockIdx.z;
  const char* Ac = (const char*)(A + (size_t)bz * aStride);
  const char* Bc = (const char*)(Bt + (size_t)bz * btStride);
  const int m0 = blockIdx.x * 128;
  const int n0 = blockIdx.y * 128;
  const int t = threadIdx.x;
  const int w = t >> 6, l = t & 63, lr = l & 15, lk = l >> 4;
  const int wr = (w >> 1) * 64, wc = (w & 1) * 64;

  f32x4 acc[4][4];
  #pragma unroll
  for (int i = 0; i < 4; ++i)
    #pragma unroll
    for (int j = 0; j < 4; ++j) acc[i][j] = f32x4{0.f, 0.f, 0.f, 0.f};

  char* alc = (char*)a_lds;
  char* blc = (char*)b_lds;

  for (int kt = 0; kt < 4; ++kt) {
    __syncthreads();
    #pragma unroll
    for (int i = 0; i < 4; ++i) {
      int base = i * 4096 + w * 1024;
      int lin = base + l * 16;
      int sw = lin ^ (((lin >> 7) & 7) << 4);   // rows are 128B; swizzle 16B chunk
      int row = lin >> 7;
      int inr = sw & 127;
      GLOAD16(Ac + (size_t)(m0 + row) * 512 + kt * 128 + inr, alc + base);
      GLOAD16(Bc + (size_t)(n0 + row) * 512 + kt * 128 + inr, blc + base);
    }
    __syncthreads();
    #pragma unroll
    for (int ks = 0; ks < 2; ++ks) {
      bf16x8 af[4], bf[4];
      #pragma unroll
      for (int f = 0; f < 4; ++f) {
        int ra = wr + f * 16 + lr;
        int la = ra * 128 + ks * 64 + lk * 16;
        af[f] = *(const bf16x8*)(alc + (la ^ ((ra & 7) << 4)));
        int rb = wc + f * 16 + lr;
        int lb = rb * 128 + ks * 64 + lk * 16;
        bf[f] = *(const bf16x8*)(blc + (lb ^ ((rb & 7) << 4)));
      }
      #pragma unroll
      for (int mf = 0; mf < 4; ++mf)
        #pragma unroll
        for (int nf = 0; nf < 4; ++nf)
          acc[mf][nf] = MFMA_B16(af[mf], bf[nf], acc[mf][nf]);
    }
  }

  #pragma unroll
  for (int mf = 0; mf < 4; ++mf) {
    #pragma unroll
    for (int nf = 0; nf < 4; ++nf) {
      int col = n0 + wc + nf * 16 + lr;
      #pragma unroll
      for (int r = 0; r < 4; ++r) {
        int row = m0 + wr + mf * 16 + lk * 4 + r;   // C/D: col=lane&15, row=(lane>>4)*4+reg
        float val = acc[mf][nf][r];
        val += BIAS_COL ? bias[col] : bias[row];
        size_t idx = (size_t)bz * (size_t)cStride + (size_t)row * N + col;
        if (RESID) val += resid[idx];
        if (OUT_BF16) ((unsigned short*)Cout)[idx] = f2bf(val);
        else          ((float*)Cout)[idx] = val;
      }
    }
  }
}

// ---------------------------------------------------------------------------
// Flash attention v2: K-split x2 (grid 64 x B x 2), QBLK=64 (4 waves x 16 rows),
// KBLK=32 double-buffered, 2-phase prefetch schedule, 2 blocks/CU.
// q_t,k_t: (B*N, D) bf16 (q pre-scaled by 1/16); v: (B, D, N) bf16.
// Emits unnormalized bf16 O-partial + (m,l) per row; flash_merge combines.
// ---------------------------------------------------------------------------
#define KSPLIT 2
#define KRANGE (NPIX / KSPLIT)
#define KBLK 32
#define NT (KRANGE / KBLK)

__global__ __launch_bounds__(256, 2) void flash_kernel(
    const unsigned short* __restrict__ q_t, const unsigned short* __restrict__ k_t,
    const unsigned short* __restrict__ v, unsigned short* __restrict__ opart0,
    unsigned short* __restrict__ opart1, float* __restrict__ ml) {
  __shared__ __align__(16) unsigned short k_lds[2][KBLK * CH];   // 2 x 16KB
  __shared__ __align__(16) unsigned short v_lds[2][CH * KBLK];   // 2 x 16KB
  __shared__ __align__(16) uint32_t p32[4][16][20];              // 5KB, row=80B

  const int b = blockIdx.y;
  const int ksp = blockIdx.z;
  const int q0 = blockIdx.x * 64;
  const int kbase = ksp * KRANGE;
  const int t = threadIdx.x;
  const int w = t >> 6, l = t & 63, lr = l & 15, lk = l >> 4;

  // Q fragments: 16 rows per wave, 8 d-steps of 32
  bf16x8 qf[8];
  {
    const unsigned short* qp = q_t + (size_t)(b * NPIX + q0 + w * 16 + lr) * CH + lk * 8;
    #pragma unroll
    for (int ds = 0; ds < 8; ++ds) qf[ds] = *(const bf16x8*)(qp + ds * 32);
  }

  f32x4 oacc[16];
  #pragma unroll
  for (int i = 0; i < 16; ++i) oacc[i] = f32x4{0.f, 0.f, 0.f, 0.f};
  float m_r[4] = {-3e38f, -3e38f, -3e38f, -3e38f};
  float l_r[4] = {0.f, 0.f, 0.f, 0.f};

  const char* kg = (const char*)(k_t + ((size_t)b * NPIX + kbase) * CH);
  const char* vg = (const char*)(v + (size_t)b * CH * NPIX + kbase);

  // ---- staging: K tile [32 rows][256 cols] (512B rows, 3-bit XOR swizzle),
  //               V tile [256 rows][32 cols] (64B rows, linear — naturally uniform)
  #define STAGE(buf, tt)                                                          \
    {                                                                             \
      _Pragma("unroll")                                                           \
      for (int i = 0; i < 4; ++i) {                                               \
        int d = i * 4096 + w * 1024 + l * 16;                                     \
        int row = d >> 9, cb = d & 511;                                           \
        GLOAD16(kg + (size_t)((tt) * KBLK + row) * 512 + (cb ^ ((row & 7) << 4)), \
                (char*)k_lds[buf] + d);                                           \
      }                                                                           \
      _Pragma("unroll")                                                           \
      for (int i = 0; i < 4; ++i) {                                               \
        int d = i * 4096 + w * 1024 + l * 16;                                     \
        int cd = d >> 4, c = cd >> 2, oct = cd & 3;                               \
        GLOAD16(vg + (size_t)c * (NPIX * 2) + (size_t)((tt) * KBLK) * 2 + oct * 16,\
                (char*)v_lds[buf] + d);                                           \
      }                                                                           \
    }

  STAGE(0, 0);
  __syncthreads();

  int cur = 0;
  for (int it = 0; it < NT; ++it) {
    if (it < NT - 1) STAGE(cur ^ 1, it + 1);   // prefetch next tile (in flight under compute)

    const char* klc = (const char*)k_lds[cur];
    const char* vlc = (const char*)v_lds[cur];

    // S = Q K^T  (16 x 32 strip per wave)
    f32x4 sacc[2];
    sacc[0] = f32x4{0.f, 0.f, 0.f, 0.f};
    sacc[1] = f32x4{0.f, 0.f, 0.f, 0.f};
    #pragma unroll
    for (int ds = 0; ds < 8; ++ds) {
      #pragma unroll
      for (int mf = 0; mf < 2; ++mf) {
        int row = mf * 16 + lr;
        int lin = row * 512 + ds * 64 + lk * 16;
        bf16x8 kf = *(const bf16x8*)(klc + (lin ^ ((row & 7) << 4)));
        sacc[mf] = MFMA_B16(qf[ds], kf, sacc[mf]);
      }
    }

    // online softmax; row = lk*4 + r; 16 lanes (lr) share a row
    float rmax[4];
    #pragma unroll
    for (int r = 0; r < 4; ++r) {
      float mx = fmaxf(sacc[0][r], sacc[1][r]);
      #pragma unroll
      for (int msk = 1; msk < 16; msk <<= 1) mx = fmaxf(mx, __shfl_xor(mx, msk));
      rmax[r] = mx;
    }
    bool nochg = (rmax[0] <= m_r[0]) & (rmax[1] <= m_r[1]) &
                 (rmax[2] <= m_r[2]) & (rmax[3] <= m_r[3]);
    if (!__all(nochg)) {   // exact skip: only when no row's max changed
      #pragma unroll
      for (int r = 0; r < 4; ++r) {
        float mn = fmaxf(m_r[r], rmax[r]);
        float al = __expf(m_r[r] - mn);
        m_r[r] = mn;
        l_r[r] *= al;
        #pragma unroll
        for (int cf = 0; cf < 16; ++cf) oacc[cf][r] *= al;
      }
    }
    // P = exp(S - m); pack pairs of adjacent k-cols into u32 (2-way write = free)
    float rsum[4] = {0.f, 0.f, 0.f, 0.f};
    #pragma unroll
    for (int mf = 0; mf < 2; ++mf) {
      #pragma unroll
      for (int r = 0; r < 4; ++r) {
        float p = __expf(sacc[mf][r] - m_r[r]);
        rsum[r] += p;
        float pn = __shfl_xor(p, 1);           // neighbor column
        if (!(l & 1)) {
          uint32_t pk = (uint32_t)f2bf(p) | ((uint32_t)f2bf(pn) << 16);
          p32[w][lk * 4 + r][(mf * 16 + lr) >> 1] = pk;
        }
      }
    }
    #pragma unroll
    for (int r = 0; r < 4; ++r) {
      float s = rsum[r];
      #pragma unroll
      for (int msk = 1; msk < 16; msk <<= 1) s += __shfl_xor(s, msk);
      l_r[r] += s;
    }

    // O += P V^T : A-frag = P[16 x 32] (one bf16x8/lane), B-frag from v_lds
    {
      bf16x8 ap = *(const bf16x8*)((const char*)&p32[w][0][0] + lr * 80 + lk * 16);
      #pragma unroll
      for (int cf = 0; cf < 16; ++cf) {
        int lin = (cf * 16 + lr) * 64 + lk * 16;   // V [256][32]: uniform banks
        bf16x8 bv = *(const bf16x8*)(vlc + lin);
        oacc[cf] = MFMA_B16(ap, bv, oacc[cf]);
      }
    }

    __syncthreads();   // drains vmcnt(0): next tile staged; cur buffer reads done
    cur ^= 1;
  }

  // epilogue: write unnormalized bf16 O-partial + (m,l)
  {
    unsigned short* op = (ksp ? opart1 : opart0) +
                         (size_t)(b * NPIX + q0 + w * 16) * CH;
    #pragma unroll
    for (int cf = 0; cf < 16; ++cf)
      #pragma unroll
      for (int r = 0; r < 4; ++r)
        op[(size_t)(lk * 4 + r) * CH + cf * 16 + lr] = f2bf(oacc[cf][r]);
    if (lr == 0) {
      #pragma unroll
      for (int r = 0; r < 4; ++r) {
        float* mlrow = ml + ((size_t)ksp * (BATCH * NPIX) +
                             b * NPIX + q0 + w * 16 + lk * 4 + r) * 2;
        mlrow[0] = m_r[r];
        mlrow[1] = l_r[r];
      }
    }
  }
}

// ---------------------------------------------------------------------------
// Merge the two K-split partials: out = (e0*O0 + e1*O1) / (e0*l0 + e1*l1)
// In-place over opart1 (each thread owns its elements). 16 rows x 16 colgroups.
// ---------------------------------------------------------------------------
__global__ __launch_bounds__(256) void flash_merge(
    const unsigned short* __restrict__ op0, unsigned short* __restrict__ op1io,
    const float* __restrict__ ml) {
  int t = threadIdx.x;
  int gr = blockIdx.x * 16 + (t >> 4);
  int colg = (t & 15) * 16;
  float m0 = ml[(size_t)gr * 2], l0 = ml[(size_t)gr * 2 + 1];
  float m1 = ml[((size_t)(BATCH * NPIX) + gr) * 2];
  float l1 = ml[((size_t)(BATCH * NPIX) + gr) * 2 + 1];
  float m = fmaxf(m0, m1);
  float e0 = __expf(m0 - m), e1 = __expf(m1 - m);
  float inv = 1.0f / (e0 * l0 + e1 * l1);
  const bf16x8* a = (const bf16x8*)(op0 + (size_t)gr * CH + colg);
  bf16x8* bp = (bf16x8*)(op1io + (size_t)gr * CH + colg);
  #pragma unroll
  for (int h = 0; h < 2; ++h) {
    bf16x8 va = a[h], vb = bp[h], o;
    #pragma unroll
    for (int j = 0; j < 8; ++j)
      o[j] = (short)f2bf((e0 * bf2f((unsigned short)va[j]) +
                          e1 * bf2f((unsigned short)vb[j])) * inv);
    bp[h] = o;
  }
}

// ---------------------------------------------------------------------------
extern "C" void kernel_launch(void* const* d_in, const int* in_sizes, int n_in,
                              void* d_out, int out_size, void* d_ws, size_t ws_size,
                              hipStream_t stream) {
  const float* x   = (const float*)d_in[0];
  const float* gsc = (const float*)d_in[1];
  const float* gbi = (const float*)d_in[2];
  const float* Wq  = (const float*)d_in[3];
  const float* bq  = (const float*)d_in[4];
  const float* Wk  = (const float*)d_in[5];
  const float* bk  = (const float*)d_in[6];
  const float* Wv  = (const float*)d_in[7];
  const float* bv  = (const float*)d_in[8];
  const float* Wo  = (const float*)d_in[9];
  const float* bo  = (const float*)d_in[10];

  char* ws = (char*)d_ws;
  unsigned short* Wq_b = (unsigned short*)(ws);
  unsigned short* Wk_b = (unsigned short*)(ws + 131072);
  unsigned short* Wv_b = (unsigned short*)(ws + 262144);
  unsigned short* Wo_b = (unsigned short*)(ws + 393216);
  float* bq_s          = (float*)(ws + 524288);
  float* part          = (float*)(ws + 525312);
  char* big            = ws + 533504;
  unsigned short* h_t  = (unsigned short*)(big);                      // (B*N, C) bf16; reused as O-partial 0
  unsigned short* q_t  = (unsigned short*)(big + 1 * 8388608ull);     // (B*N, C)
  unsigned short* k_t  = (unsigned short*)(big + 2 * 8388608ull);     // (B*N, C)
  unsigned short* v_   = (unsigned short*)(big + 3 * 8388608ull);     // (B, C, N)
  unsigned short* o_t  = (unsigned short*)(big + 4 * 8388608ull);     // O-partial 1 -> merged (B*N, C)
  float* ml            = (float*)(big + 5 * 8388608ull);              // [2][B*N][2] f32, 256KB
  if (ws_size < 533504 + 5ull * 8388608ull + 262144ull) return;

  wconv<<<256, 256, 0, stream>>>(Wq, Wk, Wv, Wo, bq, Wq_b, Wk_b, Wv_b, Wo_b, bq_s);
  gn_stats<<<BATCH * CH, 256, 0, stream>>>(x, part);
  gn_apply<<<dim3(64, NGROUP, BATCH), 256, 0, stream>>>(x, part, gsc, gbi, h_t);

  // q_t = h_t @ (Wq/16)^T + bq/16 ; k_t = h_t @ Wk^T + bk   (M=16384, N=256)
  gemm_bt_k<1, 0, 1><<<dim3(128, 2, 1), 256, 0, stream>>>(
      h_t, Wq_b, q_t, bq_s, nullptr, 16384, 256, 0, 0, 0);
  gemm_bt_k<1, 0, 1><<<dim3(128, 2, 1), 256, 0, stream>>>(
      h_t, Wk_b, k_t, bk, nullptr, 16384, 256, 0, 0, 0);
  // v = Wv @ h + bv, stored (C, N) per batch  (M=256, N=4096)
  gemm_bt_k<0, 0, 1><<<dim3(2, 32, BATCH), 256, 0, stream>>>(
      Wv_b, h_t, v_, bv, nullptr, 256, 4096, 0, 1048576, 1048576);

  // flash: h_t is dead now -> O-partial 0; o_t -> O-partial 1
  flash_kernel<<<dim3(64, BATCH, KSPLIT), 256, 0, stream>>>(q_t, k_t, v_, h_t, o_t, ml);
  flash_merge<<<(BATCH * NPIX) / 16, 256, 0, stream>>>(h_t, o_t, ml);

  // out = Wo @ attn_out + bo + input  (fp32, (B, C, N))
  gemm_bt_k<0, 1, 0><<<dim3(2, 32, BATCH), 256, 0, stream>>>(
      Wo_b, o_t, (float*)d_out, bo, x, 256, 4096, 0, 1048576, 1048576);
}

// Round 5
// 208.792 us; speedup vs baseline: 1.1967x; 1.1583x over previous
//
#include <hip/hip_runtime.h>
#include <stdint.h>

// Problem constants
#define BATCH 4
#define CH 256
#define NPIX 4096
#define NGROUP 8
#define GCH 32
#define EPSV 1e-5f

typedef __attribute__((ext_vector_type(8))) short bf16x8;   // 8 bf16 = 4 VGPRs
typedef __attribute__((ext_vector_type(4))) float f32x4;
typedef __attribute__((ext_vector_type(16))) float f32x16;

#define MFMA_B16(a, b, c) __builtin_amdgcn_mfma_f32_16x16x32_bf16((a), (b), (c), 0, 0, 0)
#define MFMA32(a, b, c)   __builtin_amdgcn_mfma_f32_32x32x16_bf16((a), (b), (c), 0, 0, 0)

// global -> LDS direct copy, 16B per lane; LDS dest must be wave-uniform base + lane*16
#define GLOAD16(gsrc, ldst)                                                        \
  __builtin_amdgcn_global_load_lds(                                               \
      (const __attribute__((address_space(1))) uint32_t*)(gsrc),                  \
      (__attribute__((address_space(3))) uint32_t*)(ldst), 16, 0, 0)

__device__ __forceinline__ unsigned short f2bf(float f) {
  union { float f; uint32_t u; } v; v.f = f;
  return (unsigned short)((v.u + 0x7FFFu + ((v.u >> 16) & 1u)) >> 16);
}
__device__ __forceinline__ float bf2f(unsigned short h) {
  union { uint32_t u; float f; } v; v.u = ((uint32_t)h) << 16;
  return v.f;
}

// ---------------------------------------------------------------------------
// Weight conversion: fp32 -> bf16; fold attention scale 1/16 into Wq and bq
// ---------------------------------------------------------------------------
__global__ __launch_bounds__(256) void wconv(
    const float* __restrict__ Wq, const float* __restrict__ Wk,
    const float* __restrict__ Wv, const float* __restrict__ Wo,
    const float* __restrict__ bq,
    unsigned short* __restrict__ Wq_b, unsigned short* __restrict__ Wk_b,
    unsigned short* __restrict__ Wv_b, unsigned short* __restrict__ Wo_b,
    float* __restrict__ bq_s) {
  int i = blockIdx.x * 256 + threadIdx.x;   // 65536 per weight
  Wq_b[i] = f2bf(Wq[i] * 0.0625f);
  Wk_b[i] = f2bf(Wk[i]);
  Wv_b[i] = f2bf(Wv[i]);
  Wo_b[i] = f2bf(Wo[i]);
  if (i < CH) bq_s[i] = bq[i] * 0.0625f;
}

// ---------------------------------------------------------------------------
// GroupNorm pass 1: per-(b,c) partial sums (deterministic; no atomics)
// ---------------------------------------------------------------------------
__global__ __launch_bounds__(256) void gn_stats(const float* __restrict__ x,
                                                float* __restrict__ part) {
  int bc = blockIdx.x;                       // 0 .. B*C-1
  const float* row = x + (size_t)bc * NPIX;
  int t = threadIdx.x;
  float s = 0.f, ss = 0.f;
  #pragma unroll
  for (int i = 0; i < 4; ++i) {
    f32x4 v = *(const f32x4*)(row + (i * 256 + t) * 4);
    s += v[0] + v[1] + v[2] + v[3];
    ss += v[0]*v[0] + v[1]*v[1] + v[2]*v[2] + v[3]*v[3];
  }
  #pragma unroll
  for (int m = 1; m < 64; m <<= 1) { s += __shfl_xor(s, m); ss += __shfl_xor(ss, m); }
  __shared__ float ls[8];
  if ((t & 63) == 0) { ls[(t >> 6) * 2] = s; ls[(t >> 6) * 2 + 1] = ss; }
  __syncthreads();
  if (t == 0) {
    part[bc * 2]     = ls[0] + ls[2] + ls[4] + ls[6];
    part[bc * 2 + 1] = ls[1] + ls[3] + ls[5] + ls[7];
  }
}

// ---------------------------------------------------------------------------
// GroupNorm pass 2: normalize + affine, write h transposed (B*N, C) as bf16
// ---------------------------------------------------------------------------
__global__ __launch_bounds__(256) void gn_apply(
    const float* __restrict__ x, const float* __restrict__ part,
    const float* __restrict__ gamma, const float* __restrict__ beta,
    unsigned short* __restrict__ h_t) {
  int chunk = blockIdx.x, g = blockIdx.y, b = blockIdx.z;
  int t = threadIdx.x;
  __shared__ float s_mean, s_rstd;
  __shared__ unsigned short tile[GCH][72];   // +pad
  if (t == 0) {
    float S = 0.f, SS = 0.f;
    const float* p = part + (size_t)(b * CH + g * GCH) * 2;
    for (int j = 0; j < GCH; ++j) { S += p[2 * j]; SS += p[2 * j + 1]; }
    float inv = 1.0f / (float)(GCH * NPIX);
    float mean = S * inv;
    float var = SS * inv - mean * mean;
    s_mean = mean;
    s_rstd = rsqrtf(var + EPSV);
  }
  __syncthreads();
  float mean = s_mean, rstd = s_rstd;
  int n0 = chunk * 64;
  int p = t & 63;
  int csub = t >> 6;
  #pragma unroll
  for (int cl = 0; cl < GCH; cl += 4) {
    int c = cl + csub;
    float val = x[(size_t)(b * CH + g * GCH + c) * NPIX + n0 + p];
    float gm = gamma[g * GCH + c], bt = beta[g * GCH + c];
    tile[c][p] = f2bf((val - mean) * rstd * gm + bt);
  }
  __syncthreads();
  int pix = t >> 2, cc = (t & 3) * 8;
  bf16x8 vv;
  #pragma unroll
  for (int j = 0; j < 8; ++j) vv[j] = (short)tile[cc + j][pix];
  *(bf16x8*)(h_t + (size_t)(b * NPIX + n0 + pix) * CH + g * GCH + cc) = vv;
}

// ---------------------------------------------------------------------------
// GEMM: C[M,N] = A[M,256]bf16 * Bt[N,256]bf16^T (+bias, +resid)
// 128x128 tile, BK=64, 4 waves (2x2), XOR-swizzled LDS, global_load_lds w16
// ---------------------------------------------------------------------------
template <int BIAS_COL, int RESID, int OUT_BF16>
__global__ __launch_bounds__(256, 2) void gemm_bt_k(
    const unsigned short* __restrict__ A, const unsigned short* __restrict__ Bt,
    void* __restrict__ Cout, const float* __restrict__ bias,
    const float* __restrict__ resid, int M, int N,
    long aStride, long btStride, long cStride) {
  __shared__ __align__(16) unsigned short a_lds[128 * 64];
  __shared__ __align__(16) unsigned short b_lds[128 * 64];

  const int bz = blockIdx.z;
  const char* Ac = (const char*)(A + (size_t)bz * aStride);
  const char* Bc = (const char*)(Bt + (size_t)bz * btStride);
  const int m0 = blockIdx.x * 128;
  const int n0 = blockIdx.y * 128;
  const int t = threadIdx.x;
  const int w = t >> 6, l = t & 63, lr = l & 15, lk = l >> 4;
  const int wr = (w >> 1) * 64, wc = (w & 1) * 64;

  f32x4 acc[4][4];
  #pragma unroll
  for (int i = 0; i < 4; ++i)
    #pragma unroll
    for (int j = 0; j < 4; ++j) acc[i][j] = f32x4{0.f, 0.f, 0.f, 0.f};

  char* alc = (char*)a_lds;
  char* blc = (char*)b_lds;

  for (int kt = 0; kt < 4; ++kt) {
    __syncthreads();
    #pragma unroll
    for (int i = 0; i < 4; ++i) {
      int base = i * 4096 + w * 1024;
      int lin = base + l * 16;
      int sw = lin ^ (((lin >> 7) & 7) << 4);   // rows are 128B; swizzle 16B chunk
      int row = lin >> 7;
      int inr = sw & 127;
      GLOAD16(Ac + (size_t)(m0 + row) * 512 + kt * 128 + inr, alc + base);
      GLOAD16(Bc + (size_t)(n0 + row) * 512 + kt * 128 + inr, blc + base);
    }
    __syncthreads();
    #pragma unroll
    for (int ks = 0; ks < 2; ++ks) {
      bf16x8 af[4], bf[4];
      #pragma unroll
      for (int f = 0; f < 4; ++f) {
        int ra = wr + f * 16 + lr;
        int la = ra * 128 + ks * 64 + lk * 16;
        af[f] = *(const bf16x8*)(alc + (la ^ ((ra & 7) << 4)));
        int rb = wc + f * 16 + lr;
        int lb = rb * 128 + ks * 64 + lk * 16;
        bf[f] = *(const bf16x8*)(blc + (lb ^ ((rb & 7) << 4)));
      }
      #pragma unroll
      for (int mf = 0; mf < 4; ++mf)
        #pragma unroll
        for (int nf = 0; nf < 4; ++nf)
          acc[mf][nf] = MFMA_B16(af[mf], bf[nf], acc[mf][nf]);
    }
  }

  #pragma unroll
  for (int mf = 0; mf < 4; ++mf) {
    #pragma unroll
    for (int nf = 0; nf < 4; ++nf) {
      int col = n0 + wc + nf * 16 + lr;
      #pragma unroll
      for (int r = 0; r < 4; ++r) {
        int row = m0 + wr + mf * 16 + lk * 4 + r;   // C/D: col=lane&15, row=(lane>>4)*4+reg
        float val = acc[mf][nf][r];
        val += BIAS_COL ? bias[col] : bias[row];
        size_t idx = (size_t)bz * (size_t)cStride + (size_t)row * N + col;
        if (RESID) val += resid[idx];
        if (OUT_BF16) ((unsigned short*)Cout)[idx] = f2bf(val);
        else          ((float*)Cout)[idx] = val;
      }
    }
  }
}

// ---------------------------------------------------------------------------
// Flash attention v4: 32x32 MFMA, swapped QK^T (lane-local softmax rows),
// 4 waves x 32 q-rows (QBLK=128), KBLK=32 double-buffered, KSPLIT=4.
// q_t,k_t: (B*N, D) bf16 (q pre-scaled 1/16); v: (B, D, N) bf16.
// Emits unnormalized bf16 O-partials + (m,l); flash_merge combines 4 splits.
// ---------------------------------------------------------------------------
#define KSPLIT 4
#define KRANGE (NPIX / KSPLIT)   // 1024
#define KBLK 32
#define NT (KRANGE / KBLK)       // 32

__global__ __launch_bounds__(256, 2) void flash_kernel(
    const unsigned short* __restrict__ q_t, const unsigned short* __restrict__ k_t,
    const unsigned short* __restrict__ v,
    unsigned short* __restrict__ p0, unsigned short* __restrict__ p1,
    unsigned short* __restrict__ p2, unsigned short* __restrict__ p3,
    float* __restrict__ ml) {
  __shared__ __align__(16) unsigned short k_lds[2][KBLK * CH];   // 2 x 16KB
  __shared__ __align__(16) unsigned short v_lds[2][CH * KBLK];   // 2 x 16KB

  const int b = blockIdx.y;
  const int ksp = blockIdx.z;
  const int q0 = blockIdx.x * 128;
  const int t = threadIdx.x;
  const int w = t >> 6, l = t & 63;
  const int l31 = l & 31, hi = l >> 5;

  // Q as second (B) operand fragments: lane holds Q[q = w*32+l31][c = ds*16 + hi*8 ..+8]
  bf16x8 qf[16];
  {
    const char* qp = (const char*)(q_t + (size_t)(b * NPIX + q0 + w * 32 + l31) * CH);
    #pragma unroll
    for (int ds = 0; ds < 16; ++ds)
      qf[ds] = *(const bf16x8*)(qp + ds * 32 + hi * 16);
  }

  f32x16 oacc[8];
  #pragma unroll
  for (int cf = 0; cf < 8; ++cf)
    #pragma unroll
    for (int r = 0; r < 16; ++r) oacc[cf][r] = 0.f;
  float m_run = -3e38f, l_run = 0.f;

  const char* kg = (const char*)(k_t + ((size_t)b * NPIX + ksp * KRANGE) * CH);
  const char* vg = (const char*)(v + (size_t)b * CH * NPIX + ksp * KRANGE);

  // K tile [32 rows][512B] with 3-bit XOR chunk swizzle;
  // V tile [256 rows][64B] with 2-bit XOR chunk swizzle (pre-swizzled source).
  #define STAGE(buf, tt)                                                           \
    {                                                                              \
      _Pragma("unroll")                                                            \
      for (int i_ = 0; i_ < 4; ++i_) {                                             \
        int d = i_ * 4096 + w * 1024 + l * 16;                                     \
        int row = d >> 9, cb = d & 511;                                            \
        GLOAD16(kg + (size_t)((tt) * KBLK + row) * 512 + (cb ^ ((row & 7) << 4)),  \
                (char*)k_lds[buf] + d);                                            \
      }                                                                            \
      _Pragma("unroll")                                                            \
      for (int i_ = 0; i_ < 4; ++i_) {                                             \
        int d = i_ * 4096 + w * 1024 + l * 16;                                     \
        int c_ = d >> 6, oct = (d >> 4) & 3;                                       \
        GLOAD16(vg + (size_t)c_ * (NPIX * 2) + (size_t)(tt) * 64 +                 \
                    ((oct ^ ((c_ >> 1) & 3)) << 4),                                \
                (char*)v_lds[buf] + d);                                            \
      }                                                                            \
    }

  STAGE(0, 0);
  __syncthreads();

  int cur = 0;
  for (int it = 0; it < NT; ++it) {
    if (it < NT - 1) STAGE(cur ^ 1, it + 1);   // prefetch stays in flight under compute

    const char* klc = (const char*)k_lds[cur];
    const char* vlc = (const char*)v_lds[cur];

    // S^T = K Q^T (swapped): lane holds S[q = l31][k = (r&3)+8*(r>>2)+4*hi], r=0..15
    f32x16 sacc;
    #pragma unroll
    for (int r = 0; r < 16; ++r) sacc[r] = 0.f;
    #pragma unroll
    for (int ds = 0; ds < 16; ++ds) {
      int lin = l31 * 512 + ds * 32 + hi * 16;
      bf16x8 kf = *(const bf16x8*)(klc + (lin ^ ((l31 & 7) << 4)));
      sacc = MFMA32(kf, qf[ds], sacc);
    }

    // online softmax: row max is 15 in-lane fmax + one cross-half shuffle
    float tm = sacc[0];
    #pragma unroll
    for (int r = 1; r < 16; ++r) tm = fmaxf(tm, sacc[r]);
    tm = fmaxf(tm, __shfl_xor(tm, 32));

    if (!__all(tm <= m_run)) {   // exact skip: only when no row's max changed
      float mn = fmaxf(m_run, tm);
      float al = __expf(m_run - mn);
      m_run = mn;
      l_run *= al;
      #pragma unroll
      for (int r = 0; r < 16; ++r) {
        float alr = __shfl(al, (r & 3) + 8 * (r >> 2) + 4 * hi);
        #pragma unroll
        for (int cf = 0; cf < 8; ++cf) oacc[cf][r] *= alr;
      }
    }

    // P = exp(S - m), packed in-register; pk[m]: k-pair {8*(m>>1)+4*hi+2*(m&1), +1}
    float ps = 0.f;
    uint32_t pk[8];
    #pragma unroll
    for (int m = 0; m < 8; ++m) {
      float pa = __expf(sacc[2 * m] - m_run);
      float pb = __expf(sacc[2 * m + 1] - m_run);
      ps += pa + pb;
      pk[m] = (uint32_t)f2bf(pa) | ((uint32_t)f2bf(pb) << 16);
    }
    ps += __shfl_xor(ps, 32);
    l_run += ps;

    // O += P V : two k-steps of 16; A-frag built from own + cross-half pk
    #pragma unroll
    for (int s = 0; s < 2; ++s) {
      uint32_t own0 = hi ? pk[4 * s + 2] : pk[4 * s + 0];
      uint32_t own1 = hi ? pk[4 * s + 3] : pk[4 * s + 1];
      uint32_t snd0 = hi ? pk[4 * s + 0] : pk[4 * s + 2];
      uint32_t snd1 = hi ? pk[4 * s + 1] : pk[4 * s + 3];
      uint32_t rcv0 = (uint32_t)__shfl_xor((int)snd0, 32);
      uint32_t rcv1 = (uint32_t)__shfl_xor((int)snd1, 32);
      union { uint32_t u[4]; bf16x8 v8; } apu;
      apu.u[0] = hi ? rcv0 : own0;   // k = 16s+8hi+{0,1}
      apu.u[1] = hi ? rcv1 : own1;   // k = 16s+8hi+{2,3}
      apu.u[2] = hi ? own0 : rcv0;   // k = 16s+8hi+{4,5}
      apu.u[3] = hi ? own1 : rcv1;   // k = 16s+8hi+{6,7}
      bf16x8 ap = apu.v8;
      #pragma unroll
      for (int cf = 0; cf < 8; ++cf) {
        int c = cf * 32 + l31;
        int lin = c * 64 + (((s * 2 + hi) ^ ((l31 >> 1) & 3)) << 4);
        bf16x8 bv = *(const bf16x8*)(vlc + lin);
        oacc[cf] = MFMA32(ap, bv, oacc[cf]);
      }
    }

    __syncthreads();   // drains staged loads; cur buffer reads done
    cur ^= 1;
  }

  // epilogue: unnormalized bf16 O-partial + (m,l)
  {
    unsigned short* opart = (ksp == 0) ? p0 : (ksp == 1) ? p1 : (ksp == 2) ? p2 : p3;
    unsigned short* op = opart + (size_t)(b * NPIX + q0 + w * 32) * CH;
    #pragma unroll
    for (int cf = 0; cf < 8; ++cf)
      #pragma unroll
      for (int r = 0; r < 16; ++r)
        op[(size_t)((r & 3) + 8 * (r >> 2) + 4 * hi) * CH + cf * 32 + l31] =
            f2bf(oacc[cf][r]);
    if (l < 32) {
      float* mlrow = ml + ((size_t)ksp * (BATCH * NPIX) +
                           b * NPIX + q0 + w * 32 + l) * 2;
      mlrow[0] = m_run;
      mlrow[1] = l_run;
    }
  }
}

// ---------------------------------------------------------------------------
// Merge 4 K-split partials: out = sum(e_i O_i) / sum(e_i l_i), in-place on p1
// ---------------------------------------------------------------------------
__global__ __launch_bounds__(256) void flash_merge(
    const unsigned short* __restrict__ p0, unsigned short* __restrict__ p1io,
    const unsigned short* __restrict__ p2, const unsigned short* __restrict__ p3,
    const float* __restrict__ ml) {
  const int R = BATCH * NPIX;
  int t = threadIdx.x;
  int gr = blockIdx.x * 16 + (t >> 4);
  int colg = (t & 15) * 16;
  float m0 = ml[(size_t)gr * 2],           l0 = ml[(size_t)gr * 2 + 1];
  float m1 = ml[((size_t)R + gr) * 2],     l1 = ml[((size_t)R + gr) * 2 + 1];
  float m2 = ml[((size_t)2 * R + gr) * 2], l2 = ml[((size_t)2 * R + gr) * 2 + 1];
  float m3 = ml[((size_t)3 * R + gr) * 2], l3 = ml[((size_t)3 * R + gr) * 2 + 1];
  float m = fmaxf(fmaxf(m0, m1), fmaxf(m2, m3));
  float e0 = __expf(m0 - m), e1 = __expf(m1 - m);
  float e2 = __expf(m2 - m), e3 = __expf(m3 - m);
  float inv = 1.0f / (e0 * l0 + e1 * l1 + e2 * l2 + e3 * l3);
  const bf16x8* a0 = (const bf16x8*)(p0 + (size_t)gr * CH + colg);
  bf16x8*       a1 = (bf16x8*)(p1io + (size_t)gr * CH + colg);
  const bf16x8* a2 = (const bf16x8*)(p2 + (size_t)gr * CH + colg);
  const bf16x8* a3 = (const bf16x8*)(p3 + (size_t)gr * CH + colg);
  #pragma unroll
  for (int h = 0; h < 2; ++h) {
    bf16x8 v0 = a0[h], v1 = a1[h], v2 = a2[h], v3 = a3[h], o;
    #pragma unroll
    for (int j = 0; j < 8; ++j)
      o[j] = (short)f2bf((e0 * bf2f((unsigned short)v0[j]) +
                          e1 * bf2f((unsigned short)v1[j]) +
                          e2 * bf2f((unsigned short)v2[j]) +
                          e3 * bf2f((unsigned short)v3[j])) * inv);
    a1[h] = o;
  }
}

// ---------------------------------------------------------------------------
extern "C" void kernel_launch(void* const* d_in, const int* in_sizes, int n_in,
                              void* d_out, int out_size, void* d_ws, size_t ws_size,
                              hipStream_t stream) {
  const float* x   = (const float*)d_in[0];
  const float* gsc = (const float*)d_in[1];
  const float* gbi = (const float*)d_in[2];
  const float* Wq  = (const float*)d_in[3];
  const float* bq  = (const float*)d_in[4];
  const float* Wk  = (const float*)d_in[5];
  const float* bk  = (const float*)d_in[6];
  const float* Wv  = (const float*)d_in[7];
  const float* bv  = (const float*)d_in[8];
  const float* Wo  = (const float*)d_in[9];
  const float* bo  = (const float*)d_in[10];

  char* ws = (char*)d_ws;
  unsigned short* Wq_b = (unsigned short*)(ws);
  unsigned short* Wk_b = (unsigned short*)(ws + 131072);
  unsigned short* Wv_b = (unsigned short*)(ws + 262144);
  unsigned short* Wo_b = (unsigned short*)(ws + 393216);
  float* bq_s          = (float*)(ws + 524288);
  float* part          = (float*)(ws + 525312);
  char* big            = ws + 533504;
  unsigned short* h_t  = (unsigned short*)(big);                      // (B*N, C); reused as O-partial 0
  unsigned short* q_t  = (unsigned short*)(big + 1 * 8388608ull);     // (B*N, C)
  unsigned short* k_t  = (unsigned short*)(big + 2 * 8388608ull);     // (B*N, C)
  unsigned short* v_   = (unsigned short*)(big + 3 * 8388608ull);     // (B, C, N)
  unsigned short* o_t  = (unsigned short*)(big + 4 * 8388608ull);     // O-partial 1 -> merged (B*N, C)
  float* ml            = (float*)(big + 5 * 8388608ull);              // [4][B*N][2] f32, 512KB
  if (ws_size < 533504 + 5ull * 8388608ull + 524288ull) return;

  // O-partials 2 and 3 live in d_out (16MB fp32 buffer = exactly 2x 8MB bf16)
  unsigned short* dout_u = (unsigned short*)d_out;
  unsigned short* op2 = dout_u;
  unsigned short* op3 = dout_u + 4194304;

  wconv<<<256, 256, 0, stream>>>(Wq, Wk, Wv, Wo, bq, Wq_b, Wk_b, Wv_b, Wo_b, bq_s);
  gn_stats<<<BATCH * CH, 256, 0, stream>>>(x, part);
  gn_apply<<<dim3(64, NGROUP, BATCH), 256, 0, stream>>>(x, part, gsc, gbi, h_t);

  // q_t = h_t @ (Wq/16)^T + bq/16 ; k_t = h_t @ Wk^T + bk   (M=16384, N=256)
  gemm_bt_k<1, 0, 1><<<dim3(128, 2, 1), 256, 0, stream>>>(
      h_t, Wq_b, q_t, bq_s, nullptr, 16384, 256, 0, 0, 0);
  gemm_bt_k<1, 0, 1><<<dim3(128, 2, 1), 256, 0, stream>>>(
      h_t, Wk_b, k_t, bk, nullptr, 16384, 256, 0, 0, 0);
  // v = Wv @ h + bv, stored (C, N) per batch  (M=256, N=4096)
  gemm_bt_k<0, 0, 1><<<dim3(2, 32, BATCH), 256, 0, stream>>>(
      Wv_b, h_t, v_, bv, nullptr, 256, 4096, 0, 1048576, 1048576);

  // flash: h_t dead -> partial0; o_t -> partial1; d_out halves -> partial2/3
  flash_kernel<<<dim3(32, BATCH, KSPLIT), 256, 0, stream>>>(
      q_t, k_t, v_, h_t, o_t, op2, op3, ml);
  flash_merge<<<(BATCH * NPIX) / 16, 256, 0, stream>>>(h_t, o_t, op2, op3, ml);

  // out = Wo @ attn_out + bo + input  (fp32, (B, C, N)) — overwrites partial scratch
  gemm_bt_k<0, 1, 0><<<dim3(2, 32, BATCH), 256, 0, stream>>>(
      Wo_b, o_t, (float*)d_out, bo, x, 256, 4096, 0, 1048576, 1048576);
}

// Round 6
// 170.715 us; speedup vs baseline: 1.4636x; 1.2230x over previous
//
#include <hip/hip_runtime.h>
#include <hip/hip_bf16.h>
#include <stdint.h>

// Problem constants
#define BATCH 4
#define CH 256
#define NPIX 4096
#define NGROUP 8
#define GCH 32
#define EPSV 1e-5f

typedef __attribute__((ext_vector_type(8))) short bf16x8;   // 8 bf16 = 4 VGPRs
typedef __attribute__((ext_vector_type(4))) float f32x4;
typedef __attribute__((ext_vector_type(16))) float f32x16;

#define MFMA_B16(a, b, c) __builtin_amdgcn_mfma_f32_16x16x32_bf16((a), (b), (c), 0, 0, 0)
#define MFMA32(a, b, c)   __builtin_amdgcn_mfma_f32_32x32x16_bf16((a), (b), (c), 0, 0, 0)

// global -> LDS direct copy, 16B per lane; LDS dest must be wave-uniform base + lane*16
#define GLOAD16(gsrc, ldst)                                                        \
  __builtin_amdgcn_global_load_lds(                                               \
      (const __attribute__((address_space(1))) uint32_t*)(gsrc),                  \
      (__attribute__((address_space(3))) uint32_t*)(ldst), 16, 0, 0)

__device__ __forceinline__ unsigned short f2bf(float f) {
  union { float f; uint32_t u; } v; v.f = f;
  return (unsigned short)((v.u + 0x7FFFu + ((v.u >> 16) & 1u)) >> 16);
}
__device__ __forceinline__ float bf2f(unsigned short h) {
  union { uint32_t u; float f; } v; v.u = ((uint32_t)h) << 16;
  return v.f;
}

// attention scale folded into Wq/bq, in log2 domain: 1/(16*ln2)
#define QSCALE 0.09016813306f

// ---------------------------------------------------------------------------
// Weight conversion: fp32 -> bf16; fold (scale/ln2) into Wq and bq
// ---------------------------------------------------------------------------
__global__ __launch_bounds__(256) void wconv(
    const float* __restrict__ Wq, const float* __restrict__ Wk,
    const float* __restrict__ Wv, const float* __restrict__ Wo,
    const float* __restrict__ bq,
    unsigned short* __restrict__ Wq_b, unsigned short* __restrict__ Wk_b,
    unsigned short* __restrict__ Wv_b, unsigned short* __restrict__ Wo_b,
    float* __restrict__ bq_s) {
  int i = blockIdx.x * 256 + threadIdx.x;   // 65536 per weight
  Wq_b[i] = f2bf(Wq[i] * QSCALE);
  Wk_b[i] = f2bf(Wk[i]);
  Wv_b[i] = f2bf(Wv[i]);
  Wo_b[i] = f2bf(Wo[i]);
  if (i < CH) bq_s[i] = bq[i] * QSCALE;
}

// ---------------------------------------------------------------------------
// GroupNorm pass 1: per-(b,c) partial sums (deterministic; no atomics)
// ---------------------------------------------------------------------------
__global__ __launch_bounds__(256) void gn_stats(const float* __restrict__ x,
                                                float* __restrict__ part) {
  int bc = blockIdx.x;                       // 0 .. B*C-1
  const float* row = x + (size_t)bc * NPIX;
  int t = threadIdx.x;
  float s = 0.f, ss = 0.f;
  #pragma unroll
  for (int i = 0; i < 4; ++i) {
    f32x4 v = *(const f32x4*)(row + (i * 256 + t) * 4);
    s += v[0] + v[1] + v[2] + v[3];
    ss += v[0]*v[0] + v[1]*v[1] + v[2]*v[2] + v[3]*v[3];
  }
  #pragma unroll
  for (int m = 1; m < 64; m <<= 1) { s += __shfl_xor(s, m); ss += __shfl_xor(ss, m); }
  __shared__ float ls[8];
  if ((t & 63) == 0) { ls[(t >> 6) * 2] = s; ls[(t >> 6) * 2 + 1] = ss; }
  __syncthreads();
  if (t == 0) {
    part[bc * 2]     = ls[0] + ls[2] + ls[4] + ls[6];
    part[bc * 2 + 1] = ls[1] + ls[3] + ls[5] + ls[7];
  }
}

// ---------------------------------------------------------------------------
// GroupNorm pass 2: normalize + affine, write h transposed (B*N, C) as bf16
// ---------------------------------------------------------------------------
__global__ __launch_bounds__(256) void gn_apply(
    const float* __restrict__ x, const float* __restrict__ part,
    const float* __restrict__ gamma, const float* __restrict__ beta,
    unsigned short* __restrict__ h_t) {
  int chunk = blockIdx.x, g = blockIdx.y, b = blockIdx.z;
  int t = threadIdx.x;
  __shared__ float s_mean, s_rstd;
  __shared__ unsigned short tile[GCH][72];   // +pad
  if (t == 0) {
    float S = 0.f, SS = 0.f;
    const float* p = part + (size_t)(b * CH + g * GCH) * 2;
    for (int j = 0; j < GCH; ++j) { S += p[2 * j]; SS += p[2 * j + 1]; }
    float inv = 1.0f / (float)(GCH * NPIX);
    float mean = S * inv;
    float var = SS * inv - mean * mean;
    s_mean = mean;
    s_rstd = rsqrtf(var + EPSV);
  }
  __syncthreads();
  float mean = s_mean, rstd = s_rstd;
  int n0 = chunk * 64;
  int p = t & 63;
  int csub = t >> 6;
  #pragma unroll
  for (int cl = 0; cl < GCH; cl += 4) {
    int c = cl + csub;
    float val = x[(size_t)(b * CH + g * GCH + c) * NPIX + n0 + p];
    float gm = gamma[g * GCH + c], bt = beta[g * GCH + c];
    tile[c][p] = f2bf((val - mean) * rstd * gm + bt);
  }
  __syncthreads();
  int pix = t >> 2, cc = (t & 3) * 8;
  bf16x8 vv;
  #pragma unroll
  for (int j = 0; j < 8; ++j) vv[j] = (short)tile[cc + j][pix];
  *(bf16x8*)(h_t + (size_t)(b * NPIX + n0 + pix) * CH + g * GCH + cc) = vv;
}

// ---------------------------------------------------------------------------
// GEMM: C[M,N] = A[M,256]bf16 * Bt[N,256]bf16^T (+bias, +resid)
// 128x128 tile, BK=64, 4 waves (2x2), XOR-swizzled LDS, global_load_lds w16
// ---------------------------------------------------------------------------
template <int BIAS_COL, int RESID, int OUT_BF16>
__global__ __launch_bounds__(256, 2) void gemm_bt_k(
    const unsigned short* __restrict__ A, const unsigned short* __restrict__ Bt,
    void* __restrict__ Cout, const float* __restrict__ bias,
    const float* __restrict__ resid, int M, int N,
    long aStride, long btStride, long cStride) {
  __shared__ __align__(16) unsigned short a_lds[128 * 64];
  __shared__ __align__(16) unsigned short b_lds[128 * 64];

  const int bz = blockIdx.z;
  const char* Ac = (const char*)(A + (size_t)bz * aStride);
  const char* Bc = (const char*)(Bt + (size_t)bz * btStride);
  const int m0 = blockIdx.x * 128;
  const int n0 = blockIdx.y * 128;
  const int t = threadIdx.x;
  const int w = t >> 6, l = t & 63, lr = l & 15, lk = l >> 4;
  const int wr = (w >> 1) * 64, wc = (w & 1) * 64;

  f32x4 acc[4][4];
  #pragma unroll
  for (int i = 0; i < 4; ++i)
    #pragma unroll
    for (int j = 0; j < 4; ++j) acc[i][j] = f32x4{0.f, 0.f, 0.f, 0.f};

  char* alc = (char*)a_lds;
  char* blc = (char*)b_lds;

  for (int kt = 0; kt < 4; ++kt) {
    __syncthreads();
    #pragma unroll
    for (int i = 0; i < 4; ++i) {
      int base = i * 4096 + w * 1024;
      int lin = base + l * 16;
      int sw = lin ^ (((lin >> 7) & 7) << 4);   // rows are 128B; swizzle 16B chunk
      int row = lin >> 7;
      int inr = sw & 127;
      GLOAD16(Ac + (size_t)(m0 + row) * 512 + kt * 128 + inr, alc + base);
      GLOAD16(Bc + (size_t)(n0 + row) * 512 + kt * 128 + inr, blc + base);
    }
    __syncthreads();
    #pragma unroll
    for (int ks = 0; ks < 2; ++ks) {
      bf16x8 af[4], bf[4];
      #pragma unroll
      for (int f = 0; f < 4; ++f) {
        int ra = wr + f * 16 + lr;
        int la = ra * 128 + ks * 64 + lk * 16;
        af[f] = *(const bf16x8*)(alc + (la ^ ((ra & 7) << 4)));
        int rb = wc + f * 16 + lr;
        int lb = rb * 128 + ks * 64 + lk * 16;
        bf[f] = *(const bf16x8*)(blc + (lb ^ ((rb & 7) << 4)));
      }
      #pragma unroll
      for (int mf = 0; mf < 4; ++mf)
        #pragma unroll
        for (int nf = 0; nf < 4; ++nf)
          acc[mf][nf] = MFMA_B16(af[mf], bf[nf], acc[mf][nf]);
    }
  }

  #pragma unroll
  for (int mf = 0; mf < 4; ++mf) {
    #pragma unroll
    for (int nf = 0; nf < 4; ++nf) {
      int col = n0 + wc + nf * 16 + lr;
      #pragma unroll
      for (int r = 0; r < 4; ++r) {
        int row = m0 + wr + mf * 16 + lk * 4 + r;   // C/D: col=lane&15, row=(lane>>4)*4+reg
        float val = acc[mf][nf][r];
        val += BIAS_COL ? bias[col] : bias[row];
        size_t idx = (size_t)bz * (size_t)cStride + (size_t)row * N + col;
        if (RESID) val += resid[idx];
        if (OUT_BF16) ((unsigned short*)Cout)[idx] = f2bf(val);
        else          ((float*)Cout)[idx] = val;
      }
    }
  }
}

// ---------------------------------------------------------------------------
// Flash attention v5: 32x32 MFMA, swapped QK^T, lane-local softmax (log2
// domain), KBLK=32, 2-tile-deep pipeline with counted vmcnt(8) + raw
// s_barrier, conflict-free 5-bit XOR LDS for both K and V, KSPLIT=4,
// XCD-aware block swizzle. Emits unnormalized partials + (m,l).
// ---------------------------------------------------------------------------
#define KSPLIT 4
#define KRANGE (NPIX / KSPLIT)   // 1024
#define KBLK 32
#define NT (KRANGE / KBLK)       // 32

__global__ __launch_bounds__(256, 2) void flash_kernel(
    const unsigned short* __restrict__ q_t, const unsigned short* __restrict__ k_t,
    const unsigned short* __restrict__ v,
    unsigned short* __restrict__ p0, unsigned short* __restrict__ p1,
    unsigned short* __restrict__ p2, unsigned short* __restrict__ p3,
    float* __restrict__ ml) {
  // Both tiles stored as 32 rows x 512B, 16B chunks XOR-swizzled by row&31.
  // K row r = pixel r of tile; chunk c = d-range [c*8, c*8+8).
  // V row r = channel&31; chunk c: channel = (c>>2)*32 + r, pix-range (c&3)*8.
  __shared__ __align__(16) unsigned short k_lds[2][KBLK * CH];   // 2 x 16KB
  __shared__ __align__(16) unsigned short v_lds[2][CH * KBLK];   // 2 x 16KB

  // XCD swizzle: give each XCD a contiguous run of 64 blocks (one (b,ksp)
  // K/V slice = 1MB, L2-resident). HW XCD = dispatch_id % 8.
  const int F = blockIdx.x;
  const int bid = (F >> 3) + ((F & 7) << 6);
  const int qx = bid & 31, b = (bid >> 5) & 3, ksp = bid >> 7;
  const int q0 = qx * 128;
  const int t = threadIdx.x;
  const int w = t >> 6, l = t & 63;
  const int l31 = l & 31, hi = l >> 5;

  // Q as B-operand fragments: lane holds Q[q=w*32+l31][d = ds*16 + hi*8 ..+8]
  bf16x8 qf[16];
  {
    const char* qp = (const char*)(q_t + (size_t)(b * NPIX + q0 + w * 32 + l31) * CH);
    #pragma unroll
    for (int ds = 0; ds < 16; ++ds)
      qf[ds] = *(const bf16x8*)(qp + ds * 32 + hi * 16);
  }

  f32x16 oacc[8];
  #pragma unroll
  for (int cf = 0; cf < 8; ++cf)
    #pragma unroll
    for (int r = 0; r < 16; ++r) oacc[cf][r] = 0.f;
  float m_run = -3e38f, l_run = 0.f;

  const char* kg = (const char*)(k_t + ((size_t)b * NPIX + ksp * KRANGE) * CH);
  const char* vg = (const char*)(v + (size_t)b * CH * NPIX + ksp * KRANGE);

  // Staging: linear LDS dest (base + lane*16); source pre-swizzled (rule 21).
  #define STAGE(buf, tt)                                                           \
    {                                                                              \
      _Pragma("unroll")                                                            \
      for (int i_ = 0; i_ < 4; ++i_) {                                             \
        int d = i_ * 4096 + w * 1024 + l * 16;                                     \
        int r_ = d >> 9, c_ = ((d >> 4) & 31) ^ r_;                                \
        GLOAD16(kg + (size_t)((tt) * KBLK + r_) * 512 + (c_ << 4),                 \
                (char*)k_lds[buf] + d);                                            \
      }                                                                            \
      _Pragma("unroll")                                                            \
      for (int i_ = 0; i_ < 4; ++i_) {                                             \
        int d = i_ * 4096 + w * 1024 + l * 16;                                     \
        int r_ = d >> 9, c5 = ((d >> 4) & 31) ^ r_;                                \
        GLOAD16(vg + (size_t)((c5 >> 2) * 32 + r_) * (NPIX * 2) +                  \
                    (size_t)(tt) * (KBLK * 2) + ((c5 & 3) << 4),                   \
                (char*)v_lds[buf] + d);                                            \
      }                                                                            \
    }

  // Prologue: 2 tiles in flight, wait for tile 0 only (counted).
  STAGE(0, 0);
  STAGE(1, 1);
  asm volatile("s_waitcnt vmcnt(8)" ::: "memory");
  __builtin_amdgcn_s_barrier();

  int cur = 0;
  for (int it = 0; it < NT; ++it) {
    const char* klc = (const char*)k_lds[cur];
    const char* vlc = (const char*)v_lds[cur];

    // S^T = K Q^T: lane holds S[q=l31][k=(r&3)+8*(r>>2)+4*hi]; 2 acc chains
    f32x16 s0, s1;
    #pragma unroll
    for (int r = 0; r < 16; ++r) { s0[r] = 0.f; s1[r] = 0.f; }
    __builtin_amdgcn_s_setprio(1);
    #pragma unroll
    for (int ds = 0; ds < 16; ++ds) {
      bf16x8 kf = *(const bf16x8*)(klc + l31 * 512 + ((((ds << 1) + hi) ^ l31) << 4));
      if (ds & 1) s1 = MFMA32(kf, qf[ds], s1);
      else        s0 = MFMA32(kf, qf[ds], s0);
    }
    __builtin_amdgcn_s_setprio(0);
    #pragma unroll
    for (int r = 0; r < 16; ++r) s0[r] += s1[r];

    // row max (tree, log2 domain), shared across lane halves
    float t8[8];
    #pragma unroll
    for (int r = 0; r < 8; ++r) t8[r] = fmaxf(s0[r], s0[r + 8]);
    float ta = fmaxf(fmaxf(t8[0], t8[4]), fmaxf(t8[1], t8[5]));
    float tb = fmaxf(fmaxf(t8[2], t8[6]), fmaxf(t8[3], t8[7]));
    float tm = fmaxf(ta, tb);
    tm = fmaxf(tm, __shfl_xor(tm, 32));

    // T13 defer-rescale: skip unless max grew by >6 (P bounded by 2^6)
    if (!__all(tm <= m_run + 6.f)) {
      float mn = fmaxf(m_run, tm);
      float al = exp2f(m_run - mn);
      m_run = mn;
      l_run *= al;
      #pragma unroll
      for (int r = 0; r < 16; ++r) {
        float alr = __shfl(al, (r & 3) + 8 * (r >> 2) + 4 * hi);
        #pragma unroll
        for (int cf = 0; cf < 8; ++cf) oacc[cf][r] *= alr;
      }
    }

    // P = 2^(S - m), packed pairs (v_cvt_pk path)
    float ps = 0.f;
    uint32_t pk[8];
    #pragma unroll
    for (int m = 0; m < 8; ++m) {
      float pa = exp2f(s0[2 * m] - m_run);
      float pb = exp2f(s0[2 * m + 1] - m_run);
      ps += pa + pb;
      union { __hip_bfloat162 h2; uint32_t u; } cv;
      cv.h2 = __float22bfloat162_rn(make_float2(pa, pb));
      pk[m] = cv.u;
    }
    ps += __shfl_xor(ps, 32);
    l_run += ps;

    // O += P V : A-frag from own + cross-half pk; B-frag from swizzled v_lds
    __builtin_amdgcn_s_setprio(1);
    #pragma unroll
    for (int s = 0; s < 2; ++s) {
      uint32_t own0 = hi ? pk[4 * s + 2] : pk[4 * s + 0];
      uint32_t own1 = hi ? pk[4 * s + 3] : pk[4 * s + 1];
      uint32_t snd0 = hi ? pk[4 * s + 0] : pk[4 * s + 2];
      uint32_t snd1 = hi ? pk[4 * s + 1] : pk[4 * s + 3];
      uint32_t rcv0 = (uint32_t)__shfl_xor((int)snd0, 32);
      uint32_t rcv1 = (uint32_t)__shfl_xor((int)snd1, 32);
      union { uint32_t u[4]; bf16x8 v8; } apu;
      apu.u[0] = hi ? rcv0 : own0;
      apu.u[1] = hi ? rcv1 : own1;
      apu.u[2] = hi ? own0 : rcv0;
      apu.u[3] = hi ? own1 : rcv1;
      bf16x8 ap = apu.v8;
      #pragma unroll
      for (int cf = 0; cf < 8; ++cf) {
        bf16x8 bv = *(const bf16x8*)(
            vlc + l31 * 512 + ((((cf << 2) + (s << 1) + hi) ^ l31) << 4));
        oacc[cf] = MFMA32(ap, bv, oacc[cf]);
      }
    }
    __builtin_amdgcn_s_setprio(0);

    // all waves done reading buf[cur] (ds_reads consumed by MFMAs above)
    asm volatile("" ::: "memory");
    __builtin_amdgcn_s_barrier();
    if (it + 2 < NT) STAGE(cur, it + 2);          // refill freed buffer
    asm volatile("s_waitcnt vmcnt(8)" ::: "memory");  // tile it+1 landed
    __builtin_amdgcn_s_barrier();                  // all waves' loads landed
    cur ^= 1;
  }

  // epilogue: unnormalized bf16 O-partial + (m,l) (log2-domain m)
  {
    unsigned short* opart = (ksp == 0) ? p0 : (ksp == 1) ? p1 : (ksp == 2) ? p2 : p3;
    unsigned short* op = opart + (size_t)(b * NPIX + q0 + w * 32) * CH;
    #pragma unroll
    for (int cf = 0; cf < 8; ++cf)
      #pragma unroll
      for (int r = 0; r < 16; ++r)
        op[(size_t)((r & 3) + 8 * (r >> 2) + 4 * hi) * CH + cf * 32 + l31] =
            f2bf(oacc[cf][r]);
    if (l < 32) {
      float* mlrow = ml + ((size_t)ksp * (BATCH * NPIX) +
                           b * NPIX + q0 + w * 32 + l) * 2;
      mlrow[0] = m_run;
      mlrow[1] = l_run;
    }
  }
}

// ---------------------------------------------------------------------------
// Merge 4 K-split partials (log2-domain m): out = sum(e_i O_i)/sum(e_i l_i)
// ---------------------------------------------------------------------------
__global__ __launch_bounds__(256) void flash_merge(
    const unsigned short* __restrict__ p0, unsigned short* __restrict__ p1io,
    const unsigned short* __restrict__ p2, const unsigned short* __restrict__ p3,
    const float* __restrict__ ml) {
  const int R = BATCH * NPIX;
  int t = threadIdx.x;
  int gr = blockIdx.x * 16 + (t >> 4);
  int colg = (t & 15) * 16;
  float m0 = ml[(size_t)gr * 2],           l0 = ml[(size_t)gr * 2 + 1];
  float m1 = ml[((size_t)R + gr) * 2],     l1 = ml[((size_t)R + gr) * 2 + 1];
  float m2 = ml[((size_t)2 * R + gr) * 2], l2 = ml[((size_t)2 * R + gr) * 2 + 1];
  float m3 = ml[((size_t)3 * R + gr) * 2], l3 = ml[((size_t)3 * R + gr) * 2 + 1];
  float m = fmaxf(fmaxf(m0, m1), fmaxf(m2, m3));
  float e0 = exp2f(m0 - m), e1 = exp2f(m1 - m);
  float e2 = exp2f(m2 - m), e3 = exp2f(m3 - m);
  float inv = 1.0f / (e0 * l0 + e1 * l1 + e2 * l2 + e3 * l3);
  const bf16x8* a0 = (const bf16x8*)(p0 + (size_t)gr * CH + colg);
  bf16x8*       a1 = (bf16x8*)(p1io + (size_t)gr * CH + colg);
  const bf16x8* a2 = (const bf16x8*)(p2 + (size_t)gr * CH + colg);
  const bf16x8* a3 = (const bf16x8*)(p3 + (size_t)gr * CH + colg);
  #pragma unroll
  for (int h = 0; h < 2; ++h) {
    bf16x8 v0 = a0[h], v1 = a1[h], v2 = a2[h], v3 = a3[h], o;
    #pragma unroll
    for (int j = 0; j < 8; ++j)
      o[j] = (short)f2bf((e0 * bf2f((unsigned short)v0[j]) +
                          e1 * bf2f((unsigned short)v1[j]) +
                          e2 * bf2f((unsigned short)v2[j]) +
                          e3 * bf2f((unsigned short)v3[j])) * inv);
    a1[h] = o;
  }
}

// ---------------------------------------------------------------------------
extern "C" void kernel_launch(void* const* d_in, const int* in_sizes, int n_in,
                              void* d_out, int out_size, void* d_ws, size_t ws_size,
                              hipStream_t stream) {
  const float* x   = (const float*)d_in[0];
  const float* gsc = (const float*)d_in[1];
  const float* gbi = (const float*)d_in[2];
  const float* Wq  = (const float*)d_in[3];
  const float* bq  = (const float*)d_in[4];
  const float* Wk  = (const float*)d_in[5];
  const float* bk  = (const float*)d_in[6];
  const float* Wv  = (const float*)d_in[7];
  const float* bv  = (const float*)d_in[8];
  const float* Wo  = (const float*)d_in[9];
  const float* bo  = (const float*)d_in[10];

  char* ws = (char*)d_ws;
  unsigned short* Wq_b = (unsigned short*)(ws);
  unsigned short* Wk_b = (unsigned short*)(ws + 131072);
  unsigned short* Wv_b = (unsigned short*)(ws + 262144);
  unsigned short* Wo_b = (unsigned short*)(ws + 393216);
  float* bq_s          = (float*)(ws + 524288);
  float* part          = (float*)(ws + 525312);
  char* big            = ws + 533504;
  unsigned short* h_t  = (unsigned short*)(big);                      // (B*N, C); reused as O-partial 0
  unsigned short* q_t  = (unsigned short*)(big + 1 * 8388608ull);     // (B*N, C)
  unsigned short* k_t  = (unsigned short*)(big + 2 * 8388608ull);     // (B*N, C)
  unsigned short* v_   = (unsigned short*)(big + 3 * 8388608ull);     // (B, C, N)
  unsigned short* o_t  = (unsigned short*)(big + 4 * 8388608ull);     // O-partial 1 -> merged (B*N, C)
  float* ml            = (float*)(big + 5 * 8388608ull);              // [4][B*N][2] f32, 512KB
  if (ws_size < 533504 + 5ull * 8388608ull + 524288ull) return;

  // O-partials 2 and 3 live in d_out (16MB fp32 buffer = exactly 2x 8MB bf16)
  unsigned short* dout_u = (unsigned short*)d_out;
  unsigned short* op2 = dout_u;
  unsigned short* op3 = dout_u + 4194304;

  wconv<<<256, 256, 0, stream>>>(Wq, Wk, Wv, Wo, bq, Wq_b, Wk_b, Wv_b, Wo_b, bq_s);
  gn_stats<<<BATCH * CH, 256, 0, stream>>>(x, part);
  gn_apply<<<dim3(64, NGROUP, BATCH), 256, 0, stream>>>(x, part, gsc, gbi, h_t);

  // q_t = h_t @ (Wq*QSCALE)^T + bq*QSCALE ; k_t = h_t @ Wk^T + bk  (M=16384, N=256)
  gemm_bt_k<1, 0, 1><<<dim3(128, 2, 1), 256, 0, stream>>>(
      h_t, Wq_b, q_t, bq_s, nullptr, 16384, 256, 0, 0, 0);
  gemm_bt_k<1, 0, 1><<<dim3(128, 2, 1), 256, 0, stream>>>(
      h_t, Wk_b, k_t, bk, nullptr, 16384, 256, 0, 0, 0);
  // v = Wv @ h + bv, stored (C, N) per batch  (M=256, N=4096)
  gemm_bt_k<0, 0, 1><<<dim3(2, 32, BATCH), 256, 0, stream>>>(
      Wv_b, h_t, v_, bv, nullptr, 256, 4096, 0, 1048576, 1048576);

  // flash: h_t dead -> partial0; o_t -> partial1; d_out halves -> partial2/3
  flash_kernel<<<dim3(32 * BATCH * KSPLIT, 1, 1), 256, 0, stream>>>(
      q_t, k_t, v_, h_t, o_t, op2, op3, ml);
  flash_merge<<<(BATCH * NPIX) / 16, 256, 0, stream>>>(h_t, o_t, op2, op3, ml);

  // out = Wo @ attn_out + bo + input  (fp32, (B, C, N)) — overwrites partial scratch
  gemm_bt_k<0, 1, 0><<<dim3(2, 32, BATCH), 256, 0, stream>>>(
      Wo_b, o_t, (float*)d_out, bo, x, 256, 4096, 0, 1048576, 1048576);
}

// Round 7
// 146.719 us; speedup vs baseline: 1.7030x; 1.1636x over previous
//
#include <hip/hip_runtime.h>
#include <hip/hip_bf16.h>
#include <stdint.h>

// Problem constants
#define BATCH 4
#define CH 256
#define NPIX 4096
#define NGROUP 8
#define GCH 32
#define EPSV 1e-5f

typedef __attribute__((ext_vector_type(8))) short bf16x8;   // 8 bf16 = 4 VGPRs
typedef __attribute__((ext_vector_type(4))) float f32x4;
typedef __attribute__((ext_vector_type(16))) float f32x16;

#define MFMA_B16(a, b, c) __builtin_amdgcn_mfma_f32_16x16x32_bf16((a), (b), (c), 0, 0, 0)
#define MFMA32(a, b, c)   __builtin_amdgcn_mfma_f32_32x32x16_bf16((a), (b), (c), 0, 0, 0)

// global -> LDS direct copy, 16B per lane; LDS dest must be wave-uniform base + lane*16
#define GLOAD16(gsrc, ldst)                                                        \
  __builtin_amdgcn_global_load_lds(                                               \
      (const __attribute__((address_space(1))) uint32_t*)(gsrc),                  \
      (__attribute__((address_space(3))) uint32_t*)(ldst), 16, 0, 0)

__device__ __forceinline__ unsigned short f2bf(float f) {
  union { float f; uint32_t u; } v; v.f = f;
  return (unsigned short)((v.u + 0x7FFFu + ((v.u >> 16) & 1u)) >> 16);
}
__device__ __forceinline__ float bf2f(unsigned short h) {
  union { uint32_t u; float f; } v; v.u = ((uint32_t)h) << 16;
  return v.f;
}

// attention scale folded into Wq/bq, in log2 domain: 1/(16*ln2)
#define QSCALE 0.09016813306f

// ---------------------------------------------------------------------------
// Weight conversion: fp32 -> bf16; fold (scale/ln2) into Wq and bq
// ---------------------------------------------------------------------------
__global__ __launch_bounds__(256) void wconv(
    const float* __restrict__ Wq, const float* __restrict__ Wk,
    const float* __restrict__ Wv, const float* __restrict__ Wo,
    const float* __restrict__ bq,
    unsigned short* __restrict__ Wq_b, unsigned short* __restrict__ Wk_b,
    unsigned short* __restrict__ Wv_b, unsigned short* __restrict__ Wo_b,
    float* __restrict__ bq_s) {
  int i = blockIdx.x * 256 + threadIdx.x;   // 65536 per weight
  Wq_b[i] = f2bf(Wq[i] * QSCALE);
  Wk_b[i] = f2bf(Wk[i]);
  Wv_b[i] = f2bf(Wv[i]);
  Wo_b[i] = f2bf(Wo[i]);
  if (i < CH) bq_s[i] = bq[i] * QSCALE;
}

// ---------------------------------------------------------------------------
// GroupNorm pass 1: per-(b,c) partial sums (deterministic; no atomics)
// ---------------------------------------------------------------------------
__global__ __launch_bounds__(256) void gn_stats(const float* __restrict__ x,
                                                float* __restrict__ part) {
  int bc = blockIdx.x;                       // 0 .. B*C-1
  const float* row = x + (size_t)bc * NPIX;
  int t = threadIdx.x;
  float s = 0.f, ss = 0.f;
  #pragma unroll
  for (int i = 0; i < 4; ++i) {
    f32x4 v = *(const f32x4*)(row + (i * 256 + t) * 4);
    s += v[0] + v[1] + v[2] + v[3];
    ss += v[0]*v[0] + v[1]*v[1] + v[2]*v[2] + v[3]*v[3];
  }
  #pragma unroll
  for (int m = 1; m < 64; m <<= 1) { s += __shfl_xor(s, m); ss += __shfl_xor(ss, m); }
  __shared__ float ls[8];
  if ((t & 63) == 0) { ls[(t >> 6) * 2] = s; ls[(t >> 6) * 2 + 1] = ss; }
  __syncthreads();
  if (t == 0) {
    part[bc * 2]     = ls[0] + ls[2] + ls[4] + ls[6];
    part[bc * 2 + 1] = ls[1] + ls[3] + ls[5] + ls[7];
  }
}

// ---------------------------------------------------------------------------
// GroupNorm pass 2: normalize + affine, write h transposed (B*N, C) as bf16
// ---------------------------------------------------------------------------
__global__ __launch_bounds__(256) void gn_apply(
    const float* __restrict__ x, const float* __restrict__ part,
    const float* __restrict__ gamma, const float* __restrict__ beta,
    unsigned short* __restrict__ h_t) {
  int chunk = blockIdx.x, g = blockIdx.y, b = blockIdx.z;
  int t = threadIdx.x;
  __shared__ float s_mean, s_rstd;
  __shared__ unsigned short tile[GCH][72];   // +pad
  if (t == 0) {
    float S = 0.f, SS = 0.f;
    const float* p = part + (size_t)(b * CH + g * GCH) * 2;
    for (int j = 0; j < GCH; ++j) { S += p[2 * j]; SS += p[2 * j + 1]; }
    float inv = 1.0f / (float)(GCH * NPIX);
    float mean = S * inv;
    float var = SS * inv - mean * mean;
    s_mean = mean;
    s_rstd = rsqrtf(var + EPSV);
  }
  __syncthreads();
  float mean = s_mean, rstd = s_rstd;
  int n0 = chunk * 64;
  int p = t & 63;
  int csub = t >> 6;
  #pragma unroll
  for (int cl = 0; cl < GCH; cl += 4) {
    int c = cl + csub;
    float val = x[(size_t)(b * CH + g * GCH + c) * NPIX + n0 + p];
    float gm = gamma[g * GCH + c], bt = beta[g * GCH + c];
    tile[c][p] = f2bf((val - mean) * rstd * gm + bt);
  }
  __syncthreads();
  int pix = t >> 2, cc = (t & 3) * 8;
  bf16x8 vv;
  #pragma unroll
  for (int j = 0; j < 8; ++j) vv[j] = (short)tile[cc + j][pix];
  *(bf16x8*)(h_t + (size_t)(b * NPIX + n0 + pix) * CH + g * GCH + cc) = vv;
}

// ---------------------------------------------------------------------------
// GEMM: C[M,N] = A[M,256]bf16 * Bt[N,256]bf16^T (+bias, +resid)
// 128x128 tile, BK=64, 4 waves (2x2), XOR-swizzled LDS, global_load_lds w16
// ---------------------------------------------------------------------------
template <int BIAS_COL, int RESID, int OUT_BF16>
__global__ __launch_bounds__(256, 2) void gemm_bt_k(
    const unsigned short* __restrict__ A, const unsigned short* __restrict__ Bt,
    void* __restrict__ Cout, const float* __restrict__ bias,
    const float* __restrict__ resid, int M, int N,
    long aStride, long btStride, long cStride) {
  __shared__ __align__(16) unsigned short a_lds[128 * 64];
  __shared__ __align__(16) unsigned short b_lds[128 * 64];

  const int bz = blockIdx.z;
  const char* Ac = (const char*)(A + (size_t)bz * aStride);
  const char* Bc = (const char*)(Bt + (size_t)bz * btStride);
  const int m0 = blockIdx.x * 128;
  const int n0 = blockIdx.y * 128;
  const int t = threadIdx.x;
  const int w = t >> 6, l = t & 63, lr = l & 15, lk = l >> 4;
  const int wr = (w >> 1) * 64, wc = (w & 1) * 64;

  f32x4 acc[4][4];
  #pragma unroll
  for (int i = 0; i < 4; ++i)
    #pragma unroll
    for (int j = 0; j < 4; ++j) acc[i][j] = f32x4{0.f, 0.f, 0.f, 0.f};

  char* alc = (char*)a_lds;
  char* blc = (char*)b_lds;

  for (int kt = 0; kt < 4; ++kt) {
    __syncthreads();
    #pragma unroll
    for (int i = 0; i < 4; ++i) {
      int base = i * 4096 + w * 1024;
      int lin = base + l * 16;
      int sw = lin ^ (((lin >> 7) & 7) << 4);   // rows are 128B; swizzle 16B chunk
      int row = lin >> 7;
      int inr = sw & 127;
      GLOAD16(Ac + (size_t)(m0 + row) * 512 + kt * 128 + inr, alc + base);
      GLOAD16(Bc + (size_t)(n0 + row) * 512 + kt * 128 + inr, blc + base);
    }
    __syncthreads();
    #pragma unroll
    for (int ks = 0; ks < 2; ++ks) {
      bf16x8 af[4], bf[4];
      #pragma unroll
      for (int f = 0; f < 4; ++f) {
        int ra = wr + f * 16 + lr;
        int la = ra * 128 + ks * 64 + lk * 16;
        af[f] = *(const bf16x8*)(alc + (la ^ ((ra & 7) << 4)));
        int rb = wc + f * 16 + lr;
        int lb = rb * 128 + ks * 64 + lk * 16;
        bf[f] = *(const bf16x8*)(blc + (lb ^ ((rb & 7) << 4)));
      }
      #pragma unroll
      for (int mf = 0; mf < 4; ++mf)
        #pragma unroll
        for (int nf = 0; nf < 4; ++nf)
          acc[mf][nf] = MFMA_B16(af[mf], bf[nf], acc[mf][nf]);
    }
  }

  #pragma unroll
  for (int mf = 0; mf < 4; ++mf) {
    #pragma unroll
    for (int nf = 0; nf < 4; ++nf) {
      int col = n0 + wc + nf * 16 + lr;
      #pragma unroll
      for (int r = 0; r < 4; ++r) {
        int row = m0 + wr + mf * 16 + lk * 4 + r;   // C/D: col=lane&15, row=(lane>>4)*4+reg
        float val = acc[mf][nf][r];
        val += BIAS_COL ? bias[col] : bias[row];
        size_t idx = (size_t)bz * (size_t)cStride + (size_t)row * N + col;
        if (RESID) val += resid[idx];
        if (OUT_BF16) ((unsigned short*)Cout)[idx] = f2bf(val);
        else          ((float*)Cout)[idx] = val;
      }
    }
  }
}

// ---------------------------------------------------------------------------
// Flash attention v6: shifted pipeline — iteration u runs ONE merged 32-MFMA
// cluster {PV(u-1) || QK^T(u)} then softmax(u); P carried in registers.
// K(u) in kbuf[u&1]; V(u) in vbuf[u&1], consumed at iter u+1. End of iter u
// stages K(u+2)->kbuf[u&1], V(u+1)->vbuf[(u+1)&1]; vmcnt(8) = {K(u+1),V(u)}.
// 32x32 MFMA, swapped QK^T, log2-domain lane-local softmax, KSPLIT=4,
// conflict-free 5-bit XOR LDS, XCD-aware swizzle. Unnormalized partials+(m,l).
// ---------------------------------------------------------------------------
#define KSPLIT 4
#define KRANGE (NPIX / KSPLIT)   // 1024
#define KBLK 32
#define NT (KRANGE / KBLK)       // 32

__global__ __launch_bounds__(256, 2) void flash_kernel(
    const unsigned short* __restrict__ q_t, const unsigned short* __restrict__ k_t,
    const unsigned short* __restrict__ v,
    unsigned short* __restrict__ p0, unsigned short* __restrict__ p1,
    unsigned short* __restrict__ p2, unsigned short* __restrict__ p3,
    float* __restrict__ ml) {
  __shared__ __align__(16) unsigned short k_lds[2][KBLK * CH];   // 2 x 16KB
  __shared__ __align__(16) unsigned short v_lds[2][CH * KBLK];   // 2 x 16KB

  // XCD swizzle: contiguous 64-block runs per XCD (one (b,ksp) slice pair)
  const int F = blockIdx.x;
  const int bid = (F >> 3) + ((F & 7) << 6);
  const int qx = bid & 31, b = (bid >> 5) & 3, ksp = bid >> 7;
  const int q0 = qx * 128;
  const int t = threadIdx.x;
  const int w = t >> 6, l = t & 63;
  const int l31 = l & 31, hi = l >> 5;

  // Q as B-operand fragments: lane holds Q[q=w*32+l31][d = ds*16 + hi*8 ..+8]
  bf16x8 qf[16];
  {
    const char* qp = (const char*)(q_t + (size_t)(b * NPIX + q0 + w * 32 + l31) * CH);
    #pragma unroll
    for (int ds = 0; ds < 16; ++ds)
      qf[ds] = *(const bf16x8*)(qp + ds * 32 + hi * 16);
  }

  f32x16 oacc[8];
  #pragma unroll
  for (int cf = 0; cf < 8; ++cf)
    #pragma unroll
    for (int r = 0; r < 16; ++r) oacc[cf][r] = 0.f;
  float m_run = -3e38f, l_run = 0.f;
  uint32_t pkc[8];
  #pragma unroll
  for (int m = 0; m < 8; ++m) pkc[m] = 0;

  const char* kg = (const char*)(k_t + ((size_t)b * NPIX + ksp * KRANGE) * CH);
  const char* vg = (const char*)(v + (size_t)b * CH * NPIX + ksp * KRANGE);

  // Precompute per-lane staging offsets (loop-invariant; +tt*stride per tile)
  int koffb[4], voffb[4], ldsd[4];
  #pragma unroll
  for (int i_ = 0; i_ < 4; ++i_) {
    int d = i_ * 4096 + w * 1024 + l * 16;
    ldsd[i_] = d;
    int r_ = d >> 9;
    int c_ = ((d >> 4) & 31) ^ r_;
    koffb[i_] = r_ * 512 + (c_ << 4);
    voffb[i_] = ((c_ >> 2) * 32 + r_) * (NPIX * 2) + ((c_ & 3) << 4);
  }

  #define STAGE_K(buf, tt)                                                         \
    { _Pragma("unroll")                                                            \
      for (int i_ = 0; i_ < 4; ++i_)                                               \
        GLOAD16(kg + (size_t)koffb[i_] + (size_t)(tt) * (KBLK * 512),              \
                (char*)k_lds[buf] + ldsd[i_]); }
  #define STAGE_V(buf, tt)                                                         \
    { _Pragma("unroll")                                                            \
      for (int i_ = 0; i_ < 4; ++i_)                                               \
        GLOAD16(vg + (size_t)voffb[i_] + (size_t)(tt) * (KBLK * 2),                \
                (char*)v_lds[buf] + ldsd[i_]); }

  // PV: O += P(prev) * V, A-frag built from own + cross-half pkc
  auto do_pv = [&](const char* vlcx) {
    #pragma unroll
    for (int s = 0; s < 2; ++s) {
      uint32_t own0 = hi ? pkc[4 * s + 2] : pkc[4 * s + 0];
      uint32_t own1 = hi ? pkc[4 * s + 3] : pkc[4 * s + 1];
      uint32_t snd0 = hi ? pkc[4 * s + 0] : pkc[4 * s + 2];
      uint32_t snd1 = hi ? pkc[4 * s + 1] : pkc[4 * s + 3];
      uint32_t rcv0 = (uint32_t)__shfl_xor((int)snd0, 32);
      uint32_t rcv1 = (uint32_t)__shfl_xor((int)snd1, 32);
      union { uint32_t u[4]; bf16x8 v8; } apu;
      apu.u[0] = hi ? rcv0 : own0;
      apu.u[1] = hi ? rcv1 : own1;
      apu.u[2] = hi ? own0 : rcv0;
      apu.u[3] = hi ? own1 : rcv1;
      bf16x8 ap = apu.v8;
      #pragma unroll
      for (int cf = 0; cf < 8; ++cf) {
        bf16x8 bv = *(const bf16x8*)(
            vlcx + l31 * 512 + ((((cf << 2) + (s << 1) + hi) ^ l31) << 4));
        oacc[cf] = MFMA32(ap, bv, oacc[cf]);
      }
    }
  };

  // Prologue: K(0)->kbuf0, K(1)->kbuf1, V(0)->vbuf0; wait K(0) (oldest 4)
  STAGE_K(0, 0);
  STAGE_K(1, 1);
  STAGE_V(0, 0);
  asm volatile("s_waitcnt vmcnt(8)" ::: "memory");
  __builtin_amdgcn_s_barrier();

  for (int u = 0; u < NT; ++u) {
    const char* klc = (const char*)k_lds[u & 1];
    const char* vlc = (const char*)v_lds[(u ^ 1) & 1];   // V(u-1)

    __builtin_amdgcn_s_setprio(1);
    if (u > 0) do_pv(vlc);                // PV(u-1): independent of QK below
    f32x16 sacc;
    #pragma unroll
    for (int r = 0; r < 16; ++r) sacc[r] = 0.f;
    #pragma unroll
    for (int ds = 0; ds < 16; ++ds) {
      bf16x8 kf = *(const bf16x8*)(klc + l31 * 512 + ((((ds << 1) + hi) ^ l31) << 4));
      sacc = MFMA32(kf, qf[ds], sacc);
    }
    __builtin_amdgcn_s_setprio(0);

    // softmax(u): tree max, defer-rescale, P = 2^(S-m) packed into pkc
    float mx[8];
    #pragma unroll
    for (int r = 0; r < 8; ++r) mx[r] = fmaxf(sacc[r], sacc[r + 8]);
    #pragma unroll
    for (int st = 4; st >= 1; st >>= 1)
      #pragma unroll
      for (int r = 0; r < 4; ++r)
        if (r < st) mx[r] = fmaxf(mx[r], mx[r + st]);
    float tm = fmaxf(mx[0], __shfl_xor(mx[0], 32));

    if (!__all(tm <= m_run + 6.f)) {      // T13: P bounded by 2^6
      float mn = fmaxf(m_run, tm);
      float al = exp2f(m_run - mn);
      m_run = mn;
      l_run *= al;
      #pragma unroll
      for (int r = 0; r < 16; ++r) {
        float alr = __shfl(al, (r & 3) + 8 * (r >> 2) + 4 * hi);
        #pragma unroll
        for (int cf = 0; cf < 8; ++cf) oacc[cf][r] *= alr;
      }
    }

    float psp[4] = {0.f, 0.f, 0.f, 0.f};
    #pragma unroll
    for (int m = 0; m < 8; ++m) {
      float pa = exp2f(sacc[2 * m] - m_run);
      float pb = exp2f(sacc[2 * m + 1] - m_run);
      psp[m & 3] += pa + pb;
      union { __hip_bfloat162 h2; uint32_t u; } cv;
      cv.h2 = __float22bfloat162_rn(make_float2(pa, pb));
      pkc[m] = cv.u;
    }
    float ps = (psp[0] + psp[1]) + (psp[2] + psp[3]);
    ps += __shfl_xor(ps, 32);
    l_run += ps;

    asm volatile("" ::: "memory");
    __builtin_amdgcn_s_barrier();         // all waves done with kbuf[u&1], vbuf[(u-1)&1]
    if (u + 2 < NT) STAGE_K((u & 1), u + 2);
    if (u + 1 < NT) STAGE_V(((u + 1) & 1), u + 1);
    if (u + 2 < NT)      { asm volatile("s_waitcnt vmcnt(8)" ::: "memory"); }
    else if (u + 1 < NT) { asm volatile("s_waitcnt vmcnt(4)" ::: "memory"); }
    else                 { asm volatile("s_waitcnt vmcnt(0)" ::: "memory"); }
    __builtin_amdgcn_s_barrier();         // {K(u+1), V(u)} visible to all waves
  }

  // final PV(NT-1): V(NT-1) sits in vbuf[(NT-1)&1]
  __builtin_amdgcn_s_setprio(1);
  do_pv((const char*)v_lds[(NT - 1) & 1]);
  __builtin_amdgcn_s_setprio(0);

  // epilogue: unnormalized bf16 O-partial + (m,l) (log2-domain m)
  {
    unsigned short* opart = (ksp == 0) ? p0 : (ksp == 1) ? p1 : (ksp == 2) ? p2 : p3;
    unsigned short* op = opart + (size_t)(b * NPIX + q0 + w * 32) * CH;
    #pragma unroll
    for (int cf = 0; cf < 8; ++cf)
      #pragma unroll
      for (int r = 0; r < 16; ++r)
        op[(size_t)((r & 3) + 8 * (r >> 2) + 4 * hi) * CH + cf * 32 + l31] =
            f2bf(oacc[cf][r]);
    if (l < 32) {
      float* mlrow = ml + ((size_t)ksp * (BATCH * NPIX) +
                           b * NPIX + q0 + w * 32 + l) * 2;
      mlrow[0] = m_run;
      mlrow[1] = l_run;
    }
  }
  #undef STAGE_K
  #undef STAGE_V
}

// ---------------------------------------------------------------------------
// Merge 4 K-split partials (log2-domain m): out = sum(e_i O_i)/sum(e_i l_i)
// ---------------------------------------------------------------------------
__global__ __launch_bounds__(256) void flash_merge(
    const unsigned short* __restrict__ p0, unsigned short* __restrict__ p1io,
    const unsigned short* __restrict__ p2, const unsigned short* __restrict__ p3,
    const float* __restrict__ ml) {
  const int R = BATCH * NPIX;
  int t = threadIdx.x;
  int gr = blockIdx.x * 16 + (t >> 4);
  int colg = (t & 15) * 16;
  float m0 = ml[(size_t)gr * 2],           l0 = ml[(size_t)gr * 2 + 1];
  float m1 = ml[((size_t)R + gr) * 2],     l1 = ml[((size_t)R + gr) * 2 + 1];
  float m2 = ml[((size_t)2 * R + gr) * 2], l2 = ml[((size_t)2 * R + gr) * 2 + 1];
  float m3 = ml[((size_t)3 * R + gr) * 2], l3 = ml[((size_t)3 * R + gr) * 2 + 1];
  float m = fmaxf(fmaxf(m0, m1), fmaxf(m2, m3));
  float e0 = exp2f(m0 - m), e1 = exp2f(m1 - m);
  float e2 = exp2f(m2 - m), e3 = exp2f(m3 - m);
  float inv = 1.0f / (e0 * l0 + e1 * l1 + e2 * l2 + e3 * l3);
  const bf16x8* a0 = (const bf16x8*)(p0 + (size_t)gr * CH + colg);
  bf16x8*       a1 = (bf16x8*)(p1io + (size_t)gr * CH + colg);
  const bf16x8* a2 = (const bf16x8*)(p2 + (size_t)gr * CH + colg);
  const bf16x8* a3 = (const bf16x8*)(p3 + (size_t)gr * CH + colg);
  #pragma unroll
  for (int h = 0; h < 2; ++h) {
    bf16x8 v0 = a0[h], v1 = a1[h], v2 = a2[h], v3 = a3[h], o;
    #pragma unroll
    for (int j = 0; j < 8; ++j)
      o[j] = (short)f2bf((e0 * bf2f((unsigned short)v0[j]) +
                          e1 * bf2f((unsigned short)v1[j]) +
                          e2 * bf2f((unsigned short)v2[j]) +
                          e3 * bf2f((unsigned short)v3[j])) * inv);
    a1[h] = o;
  }
}

// ---------------------------------------------------------------------------
extern "C" void kernel_launch(void* const* d_in, const int* in_sizes, int n_in,
                              void* d_out, int out_size, void* d_ws, size_t ws_size,
                              hipStream_t stream) {
  const float* x   = (const float*)d_in[0];
  const float* gsc = (const float*)d_in[1];
  const float* gbi = (const float*)d_in[2];
  const float* Wq  = (const float*)d_in[3];
  const float* bq  = (const float*)d_in[4];
  const float* Wk  = (const float*)d_in[5];
  const float* bk  = (const float*)d_in[6];
  const float* Wv  = (const float*)d_in[7];
  const float* bv  = (const float*)d_in[8];
  const float* Wo  = (const float*)d_in[9];
  const float* bo  = (const float*)d_in[10];

  char* ws = (char*)d_ws;
  unsigned short* Wq_b = (unsigned short*)(ws);
  unsigned short* Wk_b = (unsigned short*)(ws + 131072);
  unsigned short* Wv_b = (unsigned short*)(ws + 262144);
  unsigned short* Wo_b = (unsigned short*)(ws + 393216);
  float* bq_s          = (float*)(ws + 524288);
  float* part          = (float*)(ws + 525312);
  char* big            = ws + 533504;
  unsigned short* h_t  = (unsigned short*)(big);                      // (B*N, C); reused as O-partial 0
  unsigned short* q_t  = (unsigned short*)(big + 1 * 8388608ull);     // (B*N, C)
  unsigned short* k_t  = (unsigned short*)(big + 2 * 8388608ull);     // (B*N, C)
  unsigned short* v_   = (unsigned short*)(big + 3 * 8388608ull);     // (B, C, N)
  unsigned short* o_t  = (unsigned short*)(big + 4 * 8388608ull);     // O-partial 1 -> merged (B*N, C)
  float* ml            = (float*)(big + 5 * 8388608ull);              // [4][B*N][2] f32, 512KB
  if (ws_size < 533504 + 5ull * 8388608ull + 524288ull) return;

  // O-partials 2 and 3 live in d_out (16MB fp32 buffer = exactly 2x 8MB bf16)
  unsigned short* dout_u = (unsigned short*)d_out;
  unsigned short* op2 = dout_u;
  unsigned short* op3 = dout_u + 4194304;

  wconv<<<256, 256, 0, stream>>>(Wq, Wk, Wv, Wo, bq, Wq_b, Wk_b, Wv_b, Wo_b, bq_s);
  gn_stats<<<BATCH * CH, 256, 0, stream>>>(x, part);
  gn_apply<<<dim3(64, NGROUP, BATCH), 256, 0, stream>>>(x, part, gsc, gbi, h_t);

  // q_t = h_t @ (Wq*QSCALE)^T + bq*QSCALE ; k_t = h_t @ Wk^T + bk  (M=16384, N=256)
  gemm_bt_k<1, 0, 1><<<dim3(128, 2, 1), 256, 0, stream>>>(
      h_t, Wq_b, q_t, bq_s, nullptr, 16384, 256, 0, 0, 0);
  gemm_bt_k<1, 0, 1><<<dim3(128, 2, 1), 256, 0, stream>>>(
      h_t, Wk_b, k_t, bk, nullptr, 16384, 256, 0, 0, 0);
  // v = Wv @ h + bv, stored (C, N) per batch  (M=256, N=4096)
  gemm_bt_k<0, 0, 1><<<dim3(2, 32, BATCH), 256, 0, stream>>>(
      Wv_b, h_t, v_, bv, nullptr, 256, 4096, 0, 1048576, 1048576);

  // flash: h_t dead -> partial0; o_t -> partial1; d_out halves -> partial2/3
  flash_kernel<<<dim3(32 * BATCH * KSPLIT, 1, 1), 256, 0, stream>>>(
      q_t, k_t, v_, h_t, o_t, op2, op3, ml);
  flash_merge<<<(BATCH * NPIX) / 16, 256, 0, stream>>>(h_t, o_t, op2, op3, ml);

  // out = Wo @ attn_out + bo + input  (fp32, (B, C, N)) — overwrites partial scratch
  gemm_bt_k<0, 1, 0><<<dim3(2, 32, BATCH), 256, 0, stream>>>(
      Wo_b, o_t, (float*)d_out, bo, x, 256, 4096, 0, 1048576, 1048576);
}